// Round 17
// baseline (779.441 us; speedup 1.0000x reference)
//
#include <hip/hip_runtime.h>
#include <hip/hip_bf16.h>

typedef __hip_bfloat16 bf16;
typedef __attribute__((ext_vector_type(8))) short short8;
typedef __attribute__((ext_vector_type(4))) float f32x4;

#define T_TOK 6272
#define D_DIM 768
#define H_DIM 3072
#define NEXP 8
#define MAXTILES 160
#define BKR 64

#define S_BARRIER() __builtin_amdgcn_s_barrier()
#define WAIT_VM4() asm volatile("s_waitcnt vmcnt(4)" ::: "memory")
#define WAIT_VM0() asm volatile("s_waitcnt vmcnt(0)" ::: "memory")

__device__ __forceinline__ void async16(void* lds, const void* g) {
  __builtin_amdgcn_global_load_lds(
      (const __attribute__((address_space(1))) void*)g,
      (__attribute__((address_space(3))) void*)lds, 16, 0, 0);
}

// gelu(x) = 0.5*x*(1+erf(x/sqrt(2))), erf via Abramowitz-Stegun 7.1.26
__device__ __forceinline__ float gelu_f(float x) {
  float z = x * 0.70710678118654752f;
  float az = fabsf(z);
  float t = 1.f / (1.f + 0.3275911f * az);
  float poly = ((((1.061405429f * t - 1.453152027f) * t + 1.421413741f) * t -
                 0.284496736f) * t + 0.254829592f) * t;
  float e = __expf(-az * az);
  float er = 1.f - poly * e;
  er = copysignf(er, z);
  return 0.5f * x * (1.f + er);
}

// XCD-chunked bijective work decode (m204): physical id -> contiguous work
// range per XCD. nwr = total real works; returns -1 if dead block.
__device__ __forceinline__ int xcd_work(int orig, int nwr) {
  if (orig >= nwr) return -1;
  int xcd = orig & 7, pos = orig >> 3;
  int q = nwr >> 3, r = nwr & 7;
  return (xcd < r ? xcd * (q + 1) : r * (q + 1) + (xcd - r) * q) + pos;
}

// ---------------- small prep kernels ----------------

__global__ void cast_hilo(const float* __restrict__ in, bf16* __restrict__ hi,
                          bf16* __restrict__ lo, int n) {
  int i = blockIdx.x * blockDim.x + threadIdx.x;
  int stride = gridDim.x * blockDim.x;
  for (; i < n; i += stride) {
    float x = in[i];
    bf16 h = __float2bfloat16(x);
    hi[i] = h;
    lo[i] = __float2bfloat16(x - __bfloat162float(h));
  }
}

// in: [B][R][C] fp32 -> out: [B][C][R] bf16   (R,C multiples of 32)
__global__ void transpose_cast(const float* __restrict__ in, bf16* __restrict__ out,
                               int R, int C) {
  __shared__ float tile[32][33];
  int b = blockIdx.z;
  const float* ib = in + (size_t)b * R * C;
  bf16* ob = out + (size_t)b * R * C;
  int r0 = blockIdx.x * 32, c0 = blockIdx.y * 32;
  int tx = threadIdx.x & 31, ty = threadIdx.x >> 5;  // 32 x 8
  for (int i = 0; i < 32; i += 8)
    tile[ty + i][tx] = ib[(size_t)(r0 + ty + i) * C + c0 + tx];
  __syncthreads();
  for (int i = 0; i < 32; i += 8)
    ob[(size_t)(c0 + ty + i) * R + r0 + tx] = __float2bfloat16(tile[tx][ty + i]);
}

__global__ void norm_learnedE(const float* __restrict__ lE, float* __restrict__ eHat) {
  int wave = threadIdx.x >> 6, lane = threadIdx.x & 63;
  for (int e = wave; e < NEXP; e += 4) {
    float v[12];
    float ss = 0.f;
    for (int j = 0; j < 12; j++) {
      v[j] = lE[e * D_DIM + lane + 64 * j];
      ss += v[j] * v[j];
    }
    for (int o = 32; o; o >>= 1) ss += __shfl_xor(ss, o);
    float rn = 1.f / fmaxf(sqrtf(ss), 1e-12f);
    for (int j = 0; j < 12; j++) eHat[e * D_DIM + lane + 64 * j] = v[j] * rn;
  }
}

// ---- router GEMM (split-bf16, K'=3*768, BK=64, swizzled, dbuf, XCD-chunk) ---

__global__ __launch_bounds__(256, 2) void gemm_router(
    const bf16* __restrict__ pHi, const bf16* __restrict__ pLo,
    const bf16* __restrict__ wHi, const bf16* __restrict__ wLo,
    float* __restrict__ y) {
  // 49 row-tiles x 6 col-blocks = 294 works; col-fast, G=8 tile groups.
  int work = xcd_work(blockIdx.x, 294);
  int tileG = work / 48;
  int rem = work - tileG * 48;
  int base = tileG * 8;
  int gl = 49 - base; if (gl > 8) gl = 8;
  int colb = rem / gl;
  int rowt = base + rem % gl;

  __shared__ __align__(16) bf16 As[2][128 * BKR];
  __shared__ __align__(16) bf16 Bs[2][128 * BKR];
  int tid = threadIdx.x, wave = tid >> 6, lane = tid & 63;
  int wr = wave >> 1, wc = wave & 1;
  int rowbase = rowt * 128, colbase = colb * 128;
  int rslot = (lane & 7) ^ (lane >> 3);

  size_t aoff[4], boff[4];
#pragma unroll
  for (int c = 0; c < 4; c++) {
    int row = 32 * wave + 8 * c + (lane >> 3);
    aoff[c] = (size_t)(rowbase + row) * D_DIM + rslot * 8;
    boff[c] = (size_t)(colbase + row) * D_DIM + rslot * 8;
  }

  auto stage = [&](int buf, int ks) {
    int term = ks / 12;
    const bf16* A = (term == 1) ? pLo : pHi;
    const bf16* B = (term == 2) ? wLo : wHi;
    int kk = (ks - term * 12) * BKR;
#pragma unroll
    for (int c = 0; c < 4; c++) {
      async16(&As[buf][(32 * wave + 8 * c) * BKR], A + aoff[c] + kk);
      async16(&Bs[buf][(32 * wave + 8 * c) * BKR], B + boff[c] + kk);
    }
  };

  f32x4 acc[4][4];
#pragma unroll
  for (int m = 0; m < 4; m++)
#pragma unroll
    for (int n = 0; n < 4; n++) acc[m][n] = 0.f;

  stage(0, 0);
  __syncthreads();
  int cur = 0;
  int q = lane >> 4, fr = lane & 15;
  for (int ks = 0; ks < 36; ks++) {
    if (ks < 35) stage(cur ^ 1, ks + 1);
    const bf16* Ac = As[cur];
    const bf16* Bc = Bs[cur];
#pragma unroll
    for (int kh = 0; kh < 2; kh++) {
      short8 af[4], bfr[4];
#pragma unroll
      for (int m = 0; m < 4; m++) {
        int row = wr * 64 + m * 16 + fr;
        int ls = ((kh << 2) + q) ^ (row & 7);
        af[m] = *(const short8*)&Ac[row * BKR + ls * 8];
      }
#pragma unroll
      for (int n = 0; n < 4; n++) {
        int row = wc * 64 + n * 16 + fr;
        int ls = ((kh << 2) + q) ^ (row & 7);
        bfr[n] = *(const short8*)&Bc[row * BKR + ls * 8];
      }
#pragma unroll
      for (int m = 0; m < 4; m++)
#pragma unroll
        for (int n = 0; n < 4; n++)
          acc[m][n] = __builtin_amdgcn_mfma_f32_16x16x32_bf16(af[m], bfr[n], acc[m][n], 0, 0, 0);
    }
    __syncthreads();
    cur ^= 1;
  }
  for (int m = 0; m < 4; m++)
    for (int n = 0; n < 4; n++)
      for (int j = 0; j < 4; j++) {
        int r = rowbase + wr * 64 + m * 16 + (lane >> 4) * 4 + j;
        int c = colbase + wc * 64 + n * 16 + (lane & 15);
        y[(size_t)r * D_DIM + c] = acc[m][n][j];
      }
}

// ---------------- router epilogue ----------------

__global__ void router_epi(const float* __restrict__ y, const float* __restrict__ eHat,
                           const float* __restrict__ bias, int* __restrict__ gidx,
                           float* __restrict__ gval, int* __restrict__ counts) {
  int wave = threadIdx.x >> 6, lane = threadIdx.x & 63;
  int t = blockIdx.x * 4 + wave;
  float v[12];
  float ss = 0.f;
  for (int j = 0; j < 12; j++) {
    v[j] = y[(size_t)t * D_DIM + lane + 64 * j];
    ss += v[j] * v[j];
  }
  for (int o = 32; o; o >>= 1) ss += __shfl_xor(ss, o);
  float d[NEXP];
  for (int e = 0; e < NEXP; e++) {
    float s = 0.f;
    for (int j = 0; j < 12; j++) s += v[j] * eHat[e * D_DIM + lane + 64 * j];
    for (int o = 32; o; o >>= 1) s += __shfl_xor(s, o);
    d[e] = s;
  }
  if (lane == 0) {
    float rn = 1.f / fmaxf(sqrtf(ss), 1e-12f);
    float sc[NEXP], mx = -1e30f;
    for (int e = 0; e < NEXP; e++) {
      sc[e] = d[e] * rn + bias[t * NEXP + e];
      mx = fmaxf(mx, sc[e]);
    }
    float p[NEXP], sum = 0.f;
    for (int e = 0; e < NEXP; e++) {
      p[e] = expf(sc[e] - mx);
      sum += p[e];
    }
    float inv = 1.f / sum;
    int i1 = 0;
    for (int e = 1; e < NEXP; e++)
      if (sc[e] > sc[i1]) i1 = e;
    int i2 = -1;
    for (int e = 0; e < NEXP; e++) {
      if (e == i1) continue;
      if (i2 < 0 || sc[e] > sc[i2]) i2 = e;
    }
    gidx[t * 2] = i1;
    gidx[t * 2 + 1] = i2;
    gval[t * 2] = p[i1] * inv;
    gval[t * 2 + 1] = p[i2] * inv;
    atomicAdd(&counts[i1], 1);
    atomicAdd(&counts[i2], 1);
  }
}

// ---------------- segment bookkeeping (128-row tiles) ----------------

__global__ void scan_build(const int* __restrict__ counts, int* __restrict__ segstart,
                           int* __restrict__ cursors, int* __restrict__ tiles,
                           int* __restrict__ numtiles) {
  if (threadIdx.x == 0) {
    int off = 0;
    for (int e = 0; e < NEXP; e++) {
      segstart[e] = off;
      cursors[e] = off;
      off += counts[e];
    }
    segstart[NEXP] = off;              // == 2T
    segstart[NEXP + 1] = off + T_TOK;  // end of shared segment
    int nt = 0;
    for (int e = 0; e < NEXP + 1; e++) {
      int cnt = (e < NEXP) ? counts[e] : T_TOK;
      int ntl = (cnt + 127) >> 7;
      for (int l = 0; l < ntl; l++) {
        tiles[nt * 2] = e;
        tiles[nt * 2 + 1] = l;
        nt++;
      }
    }
    *numtiles = nt;
  }
}

__global__ void fill_assign(const int* __restrict__ gidx, int* __restrict__ cursors,
                            int* __restrict__ rowtok, int* __restrict__ slot_of) {
  int t = blockIdx.x * 256 + threadIdx.x;
  if (t >= T_TOK) return;
  for (int k = 0; k < 2; k++) {
    int e = gidx[t * 2 + k];
    int pos = atomicAdd(&cursors[e], 1);
    rowtok[pos] = t;
    slot_of[t * 2 + k] = pos;
  }
  rowtok[2 * T_TOK + t] = t;  // shared segment: identity
}

// ====== 128x128 / BK=32, 3-deep counted vmcnt, UNROLL-3 (static buffers) =====
// Per iter: stage(t+2) [buf (t+2)%3, compile-time] -> ds_read(t) -> MFMA(t) ->
// vmcnt(4) [t+1 landed, t+2's 4 loads flying ~1.5 iters] -> barrier.
// XCD-chunked col-fast work order with G-tile super-groups (L2-resident A).

// ---- grouped FFN GEMM 1: h = gelu(Xg @ W1 + b1), K = 768 (24 K-steps) -------

__global__ __launch_bounds__(256, 4) void gemm_ffn1(
    const bf16* __restrict__ pHi, const bf16* __restrict__ W1T,
    const bf16* __restrict__ sW1T, const float* __restrict__ b1,
    const float* __restrict__ sb1, const int* __restrict__ segstart,
    const int* __restrict__ tiles, const int* __restrict__ numtiles,
    const int* __restrict__ rowtok, bf16* __restrict__ hbuf) {
  const int NC = 24, G = 16;
  int nt = *numtiles;
  int work = xcd_work(blockIdx.x + NC * blockIdx.y, nt * NC);
  if (work < 0) return;
  int tileG = work / (NC * G);
  int rem = work - tileG * (NC * G);
  int tbase = tileG * G;
  int gl = nt - tbase; if (gl > G) gl = G;
  int colb = rem / gl;
  int gx = tbase + rem % gl;

  int seg = tiles[gx * 2], lt = tiles[gx * 2 + 1];
  int s0 = segstart[seg] + lt * 128;
  int send = segstart[seg + 1];
  const bf16* Bw = (seg < NEXP) ? W1T + (size_t)seg * H_DIM * D_DIM : sW1T;
  const float* bb = (seg < NEXP) ? b1 + seg * H_DIM : sb1;

  __shared__ __align__(16) bf16 As[3][128 * 32];
  __shared__ __align__(16) bf16 Bs[3][128 * 32];
  int tid = threadIdx.x, wave = tid >> 6, lane = tid & 63;
  int wr = wave >> 1, wc = wave & 1;
  int colbase = colb * 128;
  int q = lane >> 4, fr = lane & 15;
  int g8 = (((lane & 3) ^ ((lane >> 3) & 3))) * 8;  // inverse-swizzled src slot
  int ls8 = (q ^ ((fr >> 1) & 3)) * 8;              // swizzled read slot

  const bf16* aptr[2];
  const bf16* bptr[2];
#pragma unroll
  for (int p = 0; p < 2; p++) {
    int r = wave * 32 + p * 16 + (lane >> 2);
    int s = s0 + r;
    if (s > send - 1) s = send - 1;
    aptr[p] = pHi + (size_t)rowtok[s] * D_DIM + g8;
    bptr[p] = Bw + (size_t)(colbase + r) * D_DIM + g8;
  }

  auto stage = [&](int buf, int ks) {
    int kk = ks * 32;
#pragma unroll
    for (int p = 0; p < 2; p++) {
      async16(&As[buf][(wave * 32 + p * 16) * 32], aptr[p] + kk);
      async16(&Bs[buf][(wave * 32 + p * 16) * 32], bptr[p] + kk);
    }
  };

  f32x4 acc[4][4];
#pragma unroll
  for (int m = 0; m < 4; m++)
#pragma unroll
    for (int n = 0; n < 4; n++) acc[m][n] = 0.f;

  WAIT_VM0();  // drain rowtok/meta vector loads so vmcnt counts only staging
  stage(0, 0);
  stage(1, 1);
  WAIT_VM4();  // tile 0 landed; tile 1 in flight
  S_BARRIER();

#define NT1 24
#pragma unroll 3
  for (int ks = 0; ks < NT1; ks++) {
    if (ks + 2 < NT1) stage((ks + 2) % 3, ks + 2);  // %3 static under unroll-3
    const bf16* Ac = As[ks % 3];
    const bf16* Bc = Bs[ks % 3];
    short8 af[4], bfr[4];
#pragma unroll
    for (int m = 0; m < 4; m++)
      af[m] = *(const short8*)&Ac[(wr * 64 + m * 16 + fr) * 32 + ls8];
#pragma unroll
    for (int n = 0; n < 4; n++)
      bfr[n] = *(const short8*)&Bc[(wc * 64 + n * 16 + fr) * 32 + ls8];
    __builtin_amdgcn_s_setprio(1);
#pragma unroll
    for (int m = 0; m < 4; m++)
#pragma unroll
      for (int n = 0; n < 4; n++)
        acc[m][n] = __builtin_amdgcn_mfma_f32_16x16x32_bf16(af[m], bfr[n], acc[m][n], 0, 0, 0);
    __builtin_amdgcn_s_setprio(0);
    if (ks + 2 < NT1) { WAIT_VM4(); } else { WAIT_VM0(); }  // t+1 landed
    S_BARRIER();
  }
#pragma unroll
  for (int n = 0; n < 4; n++) {
    int c = colbase + wc * 64 + n * 16 + fr;
    float bv = bb[c];
#pragma unroll
    for (int m = 0; m < 4; m++)
#pragma unroll
      for (int j = 0; j < 4; j++) {
        int s = s0 + wr * 64 + m * 16 + q * 4 + j;
        if (s < send) {
          float xv = acc[m][n][j] + bv;
          hbuf[(size_t)s * H_DIM + c] = __float2bfloat16(gelu_f(xv));
        }
      }
  }
}

// ---- grouped FFN GEMM 2: eo = h @ W2 + b2, K = 3072 (96 K-steps) ------------

__global__ __launch_bounds__(256, 4) void gemm_ffn2(
    const bf16* __restrict__ hbuf, const bf16* __restrict__ W2T,
    const bf16* __restrict__ sW2T, const float* __restrict__ b2,
    const float* __restrict__ sb2, const int* __restrict__ segstart,
    const int* __restrict__ tiles, const int* __restrict__ numtiles,
    float* __restrict__ moebuf) {
  const int NC = 6, G = 4;
  int nt = *numtiles;
  int work = xcd_work(blockIdx.x + NC * blockIdx.y, nt * NC);
  if (work < 0) return;
  int tileG = work / (NC * G);
  int rem = work - tileG * (NC * G);
  int tbase = tileG * G;
  int gl = nt - tbase; if (gl > G) gl = G;
  int colb = rem / gl;
  int gx = tbase + rem % gl;

  int seg = tiles[gx * 2], lt = tiles[gx * 2 + 1];
  int s0 = segstart[seg] + lt * 128;
  int send = segstart[seg + 1];
  const bf16* Bw = (seg < NEXP) ? W2T + (size_t)seg * H_DIM * D_DIM : sW2T;
  const float* bb = (seg < NEXP) ? b2 + seg * D_DIM : sb2;

  __shared__ __align__(16) bf16 As[3][128 * 32];
  __shared__ __align__(16) bf16 Bs[3][128 * 32];
  int tid = threadIdx.x, wave = tid >> 6, lane = tid & 63;
  int wr = wave >> 1, wc = wave & 1;
  int colbase = colb * 128;
  int q = lane >> 4, fr = lane & 15;
  int g8 = (((lane & 3) ^ ((lane >> 3) & 3))) * 8;
  int ls8 = (q ^ ((fr >> 1) & 3)) * 8;

  const bf16* aptr[2];
  const bf16* bptr[2];
#pragma unroll
  for (int p = 0; p < 2; p++) {
    int r = wave * 32 + p * 16 + (lane >> 2);
    int s = s0 + r;
    if (s > send - 1) s = send - 1;
    aptr[p] = hbuf + (size_t)s * H_DIM + g8;
    bptr[p] = Bw + (size_t)(colbase + r) * H_DIM + g8;
  }

  auto stage = [&](int buf, int ks) {
    int kk = ks * 32;
#pragma unroll
    for (int p = 0; p < 2; p++) {
      async16(&As[buf][(wave * 32 + p * 16) * 32], aptr[p] + kk);
      async16(&Bs[buf][(wave * 32 + p * 16) * 32], bptr[p] + kk);
    }
  };

  f32x4 acc[4][4];
#pragma unroll
  for (int m = 0; m < 4; m++)
#pragma unroll
    for (int n = 0; n < 4; n++) acc[m][n] = 0.f;

  WAIT_VM0();
  stage(0, 0);
  stage(1, 1);
  WAIT_VM4();
  S_BARRIER();

#define NT2 96
#pragma unroll 3
  for (int ks = 0; ks < NT2; ks++) {
    if (ks + 2 < NT2) stage((ks + 2) % 3, ks + 2);
    const bf16* Ac = As[ks % 3];
    const bf16* Bc = Bs[ks % 3];
    short8 af[4], bfr[4];
#pragma unroll
    for (int m = 0; m < 4; m++)
      af[m] = *(const short8*)&Ac[(wr * 64 + m * 16 + fr) * 32 + ls8];
#pragma unroll
    for (int n = 0; n < 4; n++)
      bfr[n] = *(const short8*)&Bc[(wc * 64 + n * 16 + fr) * 32 + ls8];
    __builtin_amdgcn_s_setprio(1);
#pragma unroll
    for (int m = 0; m < 4; m++)
#pragma unroll
      for (int n = 0; n < 4; n++)
        acc[m][n] = __builtin_amdgcn_mfma_f32_16x16x32_bf16(af[m], bfr[n], acc[m][n], 0, 0, 0);
    __builtin_amdgcn_s_setprio(0);
    if (ks + 2 < NT2) { WAIT_VM4(); } else { WAIT_VM0(); }
    S_BARRIER();
  }
#pragma unroll
  for (int n = 0; n < 4; n++) {
    int c = colbase + wc * 64 + n * 16 + fr;
    float bv = bb[c];
#pragma unroll
    for (int m = 0; m < 4; m++)
#pragma unroll
      for (int j = 0; j < 4; j++) {
        int s = s0 + wr * 64 + m * 16 + q * 4 + j;
        if (s < send) moebuf[(size_t)s * D_DIM + c] = acc[m][n][j] + bv;
      }
  }
}

// ---------------- final combine ----------------

__global__ void combine_out(const float* __restrict__ moebuf, const float* __restrict__ gval,
                            const int* __restrict__ slot_of, float* __restrict__ out) {
  int i = blockIdx.x * 256 + threadIdx.x;
  const int total = T_TOK * (D_DIM / 4);
  if (i >= total) return;
  int t = i / (D_DIM / 4), c = i % (D_DIM / 4);
  float g0 = gval[2 * t], g1 = gval[2 * t + 1];
  int sA = slot_of[2 * t], sB = slot_of[2 * t + 1];
  const f32x4* pa = (const f32x4*)(moebuf + (size_t)sA * D_DIM) + c;
  const f32x4* pb = (const f32x4*)(moebuf + (size_t)sB * D_DIM) + c;
  const f32x4* ps = (const f32x4*)(moebuf + (size_t)(2 * T_TOK + t) * D_DIM) + c;
  f32x4 r = g0 * (*pa) + g1 * (*pb) + *ps;
  ((f32x4*)out)[i] = r;
}

// ---------------- host launch ----------------

extern "C" void kernel_launch(void* const* d_in, const int* in_sizes, int n_in,
                              void* d_out, int out_size, void* d_ws, size_t ws_size,
                              hipStream_t stream) {
  const float* x = (const float*)d_in[0];
  const float* Wlinear = (const float*)d_in[1];
  const float* learnedE = (const float*)d_in[2];
  const float* bias = (const float*)d_in[3];
  const float* W1 = (const float*)d_in[4];
  const float* b1 = (const float*)d_in[5];
  const float* W2 = (const float*)d_in[6];
  const float* b2 = (const float*)d_in[7];
  const float* sW1 = (const float*)d_in[8];
  const float* sb1 = (const float*)d_in[9];
  const float* sW2 = (const float*)d_in[10];
  const float* sb2 = (const float*)d_in[11];
  float* out = (float*)d_out;

  char* ws = (char*)d_ws;
  size_t off = 0;
  auto alloc = [&](size_t bytes) {
    char* p = ws + off;
    off += (bytes + 255) & ~(size_t)255;
    return p;
  };
  float* eHat = (float*)alloc(8 * 768 * 4);
  bf16* pHi = (bf16*)alloc((size_t)T_TOK * D_DIM * 2);
  bf16* pLo = (bf16*)alloc((size_t)T_TOK * D_DIM * 2);
  bf16* wHi = (bf16*)alloc((size_t)D_DIM * D_DIM * 2);
  bf16* wLo = (bf16*)alloc((size_t)D_DIM * D_DIM * 2);
  bf16* W1T = (bf16*)alloc((size_t)NEXP * D_DIM * H_DIM * 2);
  bf16* W2T = (bf16*)alloc((size_t)NEXP * D_DIM * H_DIM * 2);
  bf16* sW1T = (bf16*)alloc((size_t)D_DIM * H_DIM * 2);
  bf16* sW2T = (bf16*)alloc((size_t)D_DIM * H_DIM * 2);
  float* y = (float*)alloc((size_t)T_TOK * D_DIM * 4);
  bf16* hbuf = (bf16*)alloc((size_t)3 * T_TOK * H_DIM * 2);
  float* moebuf = (float*)alloc((size_t)3 * T_TOK * D_DIM * 4);
  int* gidx = (int*)alloc(T_TOK * 2 * 4);
  float* gval = (float*)alloc(T_TOK * 2 * 4);
  int* rowtok = (int*)alloc(3 * T_TOK * 4);
  int* slot_of = (int*)alloc(T_TOK * 2 * 4);
  int* counts = (int*)alloc(8 * 4);
  int* segstart = (int*)alloc(10 * 4);
  int* cursors = (int*)alloc(8 * 4);
  int* numtiles = (int*)alloc(4);
  int* tiles = (int*)alloc(MAXTILES * 2 * 4);
  (void)ws_size; (void)in_sizes; (void)n_in; (void)out_size;

  hipMemsetAsync(counts, 0, 8 * 4, stream);
  norm_learnedE<<<1, 256, 0, stream>>>(learnedE, eHat);
  cast_hilo<<<2048, 256, 0, stream>>>(x, pHi, pLo, T_TOK * D_DIM);
  cast_hilo<<<1024, 256, 0, stream>>>(Wlinear, wHi, wLo, D_DIM * D_DIM);
  transpose_cast<<<dim3(D_DIM / 32, H_DIM / 32, NEXP), 256, 0, stream>>>(W1, W1T, D_DIM, H_DIM);
  transpose_cast<<<dim3(H_DIM / 32, D_DIM / 32, NEXP), 256, 0, stream>>>(W2, W2T, H_DIM, D_DIM);
  transpose_cast<<<dim3(D_DIM / 32, H_DIM / 32, 1), 256, 0, stream>>>(sW1, sW1T, D_DIM, H_DIM);
  transpose_cast<<<dim3(H_DIM / 32, D_DIM / 32, 1), 256, 0, stream>>>(sW2, sW2T, H_DIM, D_DIM);

  gemm_router<<<294, 256, 0, stream>>>(pHi, pLo, wHi, wLo, y);
  router_epi<<<T_TOK / 4, 256, 0, stream>>>(y, eHat, bias, gidx, gval, counts);
  scan_build<<<1, 64, 0, stream>>>(counts, segstart, cursors, tiles, numtiles);
  fill_assign<<<(T_TOK + 255) / 256, 256, 0, stream>>>(gidx, cursors, rowtok, slot_of);

  gemm_ffn1<<<dim3(24, MAXTILES), 256, 0, stream>>>(
      pHi, W1T, sW1T, b1, sb1, segstart, tiles, numtiles, rowtok, hbuf);
  gemm_ffn2<<<dim3(6, MAXTILES), 256, 0, stream>>>(
      hbuf, W2T, sW2T, b2, sb2, segstart, tiles, numtiles, moebuf);

  combine_out<<<(T_TOK * (D_DIM / 4) + 255) / 256, 256, 0, stream>>>(moebuf, gval, slot_of, out);
}

// Round 18
// 696.803 us; speedup vs baseline: 1.1186x; 1.1186x over previous
//
#include <hip/hip_runtime.h>
#include <hip/hip_bf16.h>

typedef __hip_bfloat16 bf16;
typedef __attribute__((ext_vector_type(8))) short short8;
typedef __attribute__((ext_vector_type(4))) float f32x4;

#define T_TOK 6272
#define D_DIM 768
#define H_DIM 3072
#define NEXP 8
#define MAXTILES 160
#define BKR 64

#define S_BARRIER() __builtin_amdgcn_s_barrier()
#define WAIT_VM4() asm volatile("s_waitcnt vmcnt(4)" ::: "memory")
#define WAIT_VM0() asm volatile("s_waitcnt vmcnt(0)" ::: "memory")

__device__ __forceinline__ void async16(void* lds, const void* g) {
  __builtin_amdgcn_global_load_lds(
      (const __attribute__((address_space(1))) void*)g,
      (__attribute__((address_space(3))) void*)lds, 16, 0, 0);
}

// gelu(x) = 0.5*x*(1+erf(x/sqrt(2))), erf via Abramowitz-Stegun 7.1.26
__device__ __forceinline__ float gelu_f(float x) {
  float z = x * 0.70710678118654752f;
  float az = fabsf(z);
  float t = 1.f / (1.f + 0.3275911f * az);
  float poly = ((((1.061405429f * t - 1.453152027f) * t + 1.421413741f) * t -
                 0.284496736f) * t + 0.254829592f) * t;
  float e = __expf(-az * az);
  float er = 1.f - poly * e;
  er = copysignf(er, z);
  return 0.5f * x * (1.f + er);
}

// XCD-chunked bijective work decode (m204): physical id -> contiguous work
// range per XCD. nwr = total real works; returns -1 if dead block.
__device__ __forceinline__ int xcd_work(int orig, int nwr) {
  if (orig >= nwr) return -1;
  int xcd = orig & 7, pos = orig >> 3;
  int q = nwr >> 3, r = nwr & 7;
  return (xcd < r ? xcd * (q + 1) : r * (q + 1) + (xcd - r) * q) + pos;
}

// ---------------- small prep kernels ----------------

__global__ void cast_hilo(const float* __restrict__ in, bf16* __restrict__ hi,
                          bf16* __restrict__ lo, int n) {
  int i = blockIdx.x * blockDim.x + threadIdx.x;
  int stride = gridDim.x * blockDim.x;
  for (; i < n; i += stride) {
    float x = in[i];
    bf16 h = __float2bfloat16(x);
    hi[i] = h;
    lo[i] = __float2bfloat16(x - __bfloat162float(h));
  }
}

// in: [B][R][C] fp32 -> out: [B][C][R] bf16   (R,C multiples of 32)
__global__ void transpose_cast(const float* __restrict__ in, bf16* __restrict__ out,
                               int R, int C) {
  __shared__ float tile[32][33];
  int b = blockIdx.z;
  const float* ib = in + (size_t)b * R * C;
  bf16* ob = out + (size_t)b * R * C;
  int r0 = blockIdx.x * 32, c0 = blockIdx.y * 32;
  int tx = threadIdx.x & 31, ty = threadIdx.x >> 5;  // 32 x 8
  for (int i = 0; i < 32; i += 8)
    tile[ty + i][tx] = ib[(size_t)(r0 + ty + i) * C + c0 + tx];
  __syncthreads();
  for (int i = 0; i < 32; i += 8)
    ob[(size_t)(c0 + ty + i) * R + r0 + tx] = __float2bfloat16(tile[tx][ty + i]);
}

__global__ void norm_learnedE(const float* __restrict__ lE, float* __restrict__ eHat) {
  int wave = threadIdx.x >> 6, lane = threadIdx.x & 63;
  for (int e = wave; e < NEXP; e += 4) {
    float v[12];
    float ss = 0.f;
    for (int j = 0; j < 12; j++) {
      v[j] = lE[e * D_DIM + lane + 64 * j];
      ss += v[j] * v[j];
    }
    for (int o = 32; o; o >>= 1) ss += __shfl_xor(ss, o);
    float rn = 1.f / fmaxf(sqrtf(ss), 1e-12f);
    for (int j = 0; j < 12; j++) eHat[e * D_DIM + lane + 64 * j] = v[j] * rn;
  }
}

// ---- router GEMM (split-bf16, K'=3*768, BK=64, swizzled, dbuf, XCD-chunk) ---

__global__ __launch_bounds__(256, 2) void gemm_router(
    const bf16* __restrict__ pHi, const bf16* __restrict__ pLo,
    const bf16* __restrict__ wHi, const bf16* __restrict__ wLo,
    float* __restrict__ y) {
  // 49 row-tiles x 6 col-blocks = 294 works; col-fast, G=8 tile groups.
  int work = xcd_work(blockIdx.x, 294);
  int tileG = work / 48;
  int rem = work - tileG * 48;
  int base = tileG * 8;
  int gl = 49 - base; if (gl > 8) gl = 8;
  int colb = rem / gl;
  int rowt = base + rem % gl;

  __shared__ __align__(16) bf16 As[2][128 * BKR];
  __shared__ __align__(16) bf16 Bs[2][128 * BKR];
  int tid = threadIdx.x, wave = tid >> 6, lane = tid & 63;
  int wr = wave >> 1, wc = wave & 1;
  int rowbase = rowt * 128, colbase = colb * 128;
  int rslot = (lane & 7) ^ (lane >> 3);

  size_t aoff[4], boff[4];
#pragma unroll
  for (int c = 0; c < 4; c++) {
    int row = 32 * wave + 8 * c + (lane >> 3);
    aoff[c] = (size_t)(rowbase + row) * D_DIM + rslot * 8;
    boff[c] = (size_t)(colbase + row) * D_DIM + rslot * 8;
  }

  auto stage = [&](int buf, int ks) {
    int term = ks / 12;
    const bf16* A = (term == 1) ? pLo : pHi;
    const bf16* B = (term == 2) ? wLo : wHi;
    int kk = (ks - term * 12) * BKR;
#pragma unroll
    for (int c = 0; c < 4; c++) {
      async16(&As[buf][(32 * wave + 8 * c) * BKR], A + aoff[c] + kk);
      async16(&Bs[buf][(32 * wave + 8 * c) * BKR], B + boff[c] + kk);
    }
  };

  f32x4 acc[4][4];
#pragma unroll
  for (int m = 0; m < 4; m++)
#pragma unroll
    for (int n = 0; n < 4; n++) acc[m][n] = 0.f;

  stage(0, 0);
  __syncthreads();
  int cur = 0;
  int q = lane >> 4, fr = lane & 15;
  for (int ks = 0; ks < 36; ks++) {
    if (ks < 35) stage(cur ^ 1, ks + 1);
    const bf16* Ac = As[cur];
    const bf16* Bc = Bs[cur];
#pragma unroll
    for (int kh = 0; kh < 2; kh++) {
      short8 af[4], bfr[4];
#pragma unroll
      for (int m = 0; m < 4; m++) {
        int row = wr * 64 + m * 16 + fr;
        int ls = ((kh << 2) + q) ^ (row & 7);
        af[m] = *(const short8*)&Ac[row * BKR + ls * 8];
      }
#pragma unroll
      for (int n = 0; n < 4; n++) {
        int row = wc * 64 + n * 16 + fr;
        int ls = ((kh << 2) + q) ^ (row & 7);
        bfr[n] = *(const short8*)&Bc[row * BKR + ls * 8];
      }
#pragma unroll
      for (int m = 0; m < 4; m++)
#pragma unroll
        for (int n = 0; n < 4; n++)
          acc[m][n] = __builtin_amdgcn_mfma_f32_16x16x32_bf16(af[m], bfr[n], acc[m][n], 0, 0, 0);
    }
    __syncthreads();
    cur ^= 1;
  }
  for (int m = 0; m < 4; m++)
    for (int n = 0; n < 4; n++)
      for (int j = 0; j < 4; j++) {
        int r = rowbase + wr * 64 + m * 16 + (lane >> 4) * 4 + j;
        int c = colbase + wc * 64 + n * 16 + (lane & 15);
        y[(size_t)r * D_DIM + c] = acc[m][n][j];
      }
}

// ---------------- router epilogue ----------------

__global__ void router_epi(const float* __restrict__ y, const float* __restrict__ eHat,
                           const float* __restrict__ bias, int* __restrict__ gidx,
                           float* __restrict__ gval, int* __restrict__ counts) {
  int wave = threadIdx.x >> 6, lane = threadIdx.x & 63;
  int t = blockIdx.x * 4 + wave;
  float v[12];
  float ss = 0.f;
  for (int j = 0; j < 12; j++) {
    v[j] = y[(size_t)t * D_DIM + lane + 64 * j];
    ss += v[j] * v[j];
  }
  for (int o = 32; o; o >>= 1) ss += __shfl_xor(ss, o);
  float d[NEXP];
  for (int e = 0; e < NEXP; e++) {
    float s = 0.f;
    for (int j = 0; j < 12; j++) s += v[j] * eHat[e * D_DIM + lane + 64 * j];
    for (int o = 32; o; o >>= 1) s += __shfl_xor(s, o);
    d[e] = s;
  }
  if (lane == 0) {
    float rn = 1.f / fmaxf(sqrtf(ss), 1e-12f);
    float sc[NEXP], mx = -1e30f;
    for (int e = 0; e < NEXP; e++) {
      sc[e] = d[e] * rn + bias[t * NEXP + e];
      mx = fmaxf(mx, sc[e]);
    }
    float p[NEXP], sum = 0.f;
    for (int e = 0; e < NEXP; e++) {
      p[e] = expf(sc[e] - mx);
      sum += p[e];
    }
    float inv = 1.f / sum;
    int i1 = 0;
    for (int e = 1; e < NEXP; e++)
      if (sc[e] > sc[i1]) i1 = e;
    int i2 = -1;
    for (int e = 0; e < NEXP; e++) {
      if (e == i1) continue;
      if (i2 < 0 || sc[e] > sc[i2]) i2 = e;
    }
    gidx[t * 2] = i1;
    gidx[t * 2 + 1] = i2;
    gval[t * 2] = p[i1] * inv;
    gval[t * 2 + 1] = p[i2] * inv;
    atomicAdd(&counts[i1], 1);
    atomicAdd(&counts[i2], 1);
  }
}

// ---------------- segment bookkeeping (128-row tiles) ----------------

__global__ void scan_build(const int* __restrict__ counts, int* __restrict__ segstart,
                           int* __restrict__ cursors, int* __restrict__ tiles,
                           int* __restrict__ numtiles) {
  if (threadIdx.x == 0) {
    int off = 0;
    for (int e = 0; e < NEXP; e++) {
      segstart[e] = off;
      cursors[e] = off;
      off += counts[e];
    }
    segstart[NEXP] = off;              // == 2T
    segstart[NEXP + 1] = off + T_TOK;  // end of shared segment
    int nt = 0;
    for (int e = 0; e < NEXP + 1; e++) {
      int cnt = (e < NEXP) ? counts[e] : T_TOK;
      int ntl = (cnt + 127) >> 7;
      for (int l = 0; l < ntl; l++) {
        tiles[nt * 2] = e;
        tiles[nt * 2 + 1] = l;
        nt++;
      }
    }
    *numtiles = nt;
  }
}

__global__ void fill_assign(const int* __restrict__ gidx, const float* __restrict__ gval,
                            int* __restrict__ cursors, int* __restrict__ rowtok,
                            float* __restrict__ slotgate) {
  int t = blockIdx.x * 256 + threadIdx.x;
  if (t >= T_TOK) return;
  for (int k = 0; k < 2; k++) {
    int e = gidx[t * 2 + k];
    int pos = atomicAdd(&cursors[e], 1);
    rowtok[pos] = t;
    slotgate[pos] = gval[t * 2 + k];
  }
  rowtok[2 * T_TOK + t] = t;       // shared segment: identity
  slotgate[2 * T_TOK + t] = 1.0f;  // shared expert weight
}

// ====== single-barrier 2-phase 128x128 / BK=32 grouped GEMM (R15 winner) =====
// Per K-step: issue STAGE(next buf) FIRST, then ds_read(cur)+MFMA, then ONE
// vmcnt(0)+barrier. XCD-chunked col-fast work order with G-tile super-groups.

// ---- grouped FFN GEMM 1: h = gelu(Xg @ W1 + b1), K = 768 (24 K-steps) -------

__global__ __launch_bounds__(256, 4) void gemm_ffn1(
    const bf16* __restrict__ pHi, const bf16* __restrict__ W1T,
    const bf16* __restrict__ sW1T, const float* __restrict__ b1,
    const float* __restrict__ sb1, const int* __restrict__ segstart,
    const int* __restrict__ tiles, const int* __restrict__ numtiles,
    const int* __restrict__ rowtok, bf16* __restrict__ hbuf) {
  const int NC = 24, G = 16;
  int nt = *numtiles;
  int work = xcd_work(blockIdx.x + NC * blockIdx.y, nt * NC);
  if (work < 0) return;
  int tileG = work / (NC * G);
  int rem = work - tileG * (NC * G);
  int tbase = tileG * G;
  int gl = nt - tbase; if (gl > G) gl = G;
  int colb = rem / gl;
  int gx = tbase + rem % gl;

  int seg = tiles[gx * 2], lt = tiles[gx * 2 + 1];
  int s0 = segstart[seg] + lt * 128;
  int send = segstart[seg + 1];
  const bf16* Bw = (seg < NEXP) ? W1T + (size_t)seg * H_DIM * D_DIM : sW1T;
  const float* bb = (seg < NEXP) ? b1 + seg * H_DIM : sb1;

  __shared__ __align__(16) bf16 As[2][128 * 32];
  __shared__ __align__(16) bf16 Bs[2][128 * 32];
  int tid = threadIdx.x, wave = tid >> 6, lane = tid & 63;
  int wr = wave >> 1, wc = wave & 1;
  int colbase = colb * 128;
  int q = lane >> 4, fr = lane & 15;
  int g8 = (((lane & 3) ^ ((lane >> 3) & 3))) * 8;  // inverse-swizzled src slot
  int ls8 = (q ^ ((fr >> 1) & 3)) * 8;              // swizzled read slot

  const bf16* aptr[2];
  const bf16* bptr[2];
#pragma unroll
  for (int p = 0; p < 2; p++) {
    int r = wave * 32 + p * 16 + (lane >> 2);
    int s = s0 + r;
    if (s > send - 1) s = send - 1;
    aptr[p] = pHi + (size_t)rowtok[s] * D_DIM + g8;
    bptr[p] = Bw + (size_t)(colbase + r) * D_DIM + g8;
  }

  auto stage = [&](int buf, int ks) {
    int kk = ks * 32;
#pragma unroll
    for (int p = 0; p < 2; p++) {
      async16(&As[buf][(wave * 32 + p * 16) * 32], aptr[p] + kk);
      async16(&Bs[buf][(wave * 32 + p * 16) * 32], bptr[p] + kk);
    }
  };

  f32x4 acc[4][4];
#pragma unroll
  for (int m = 0; m < 4; m++)
#pragma unroll
    for (int n = 0; n < 4; n++) acc[m][n] = 0.f;

  stage(0, 0);
  WAIT_VM0();
  S_BARRIER();

#define NT1 24
  for (int ks = 0; ks < NT1; ks++) {
    if (ks + 1 < NT1) stage((ks + 1) & 1, ks + 1);  // issue next-tile loads FIRST
    const bf16* Ac = As[ks & 1];
    const bf16* Bc = Bs[ks & 1];
    short8 af[4], bfr[4];
#pragma unroll
    for (int m = 0; m < 4; m++)
      af[m] = *(const short8*)&Ac[(wr * 64 + m * 16 + fr) * 32 + ls8];
#pragma unroll
    for (int n = 0; n < 4; n++)
      bfr[n] = *(const short8*)&Bc[(wc * 64 + n * 16 + fr) * 32 + ls8];
    __builtin_amdgcn_s_setprio(1);
#pragma unroll
    for (int m = 0; m < 4; m++)
#pragma unroll
      for (int n = 0; n < 4; n++)
        acc[m][n] = __builtin_amdgcn_mfma_f32_16x16x32_bf16(af[m], bfr[n], acc[m][n], 0, 0, 0);
    __builtin_amdgcn_s_setprio(0);
    WAIT_VM0();  // next-tile stores landed (had the whole read+MFMA window)
    S_BARRIER();
  }
#pragma unroll
  for (int n = 0; n < 4; n++) {
    int c = colbase + wc * 64 + n * 16 + fr;
    float bv = bb[c];
#pragma unroll
    for (int m = 0; m < 4; m++)
#pragma unroll
      for (int j = 0; j < 4; j++) {
        int s = s0 + wr * 64 + m * 16 + q * 4 + j;
        if (s < send) {
          float xv = acc[m][n][j] + bv;
          hbuf[(size_t)s * H_DIM + c] = __float2bfloat16(gelu_f(xv));
        }
      }
  }
}

// ---- grouped FFN GEMM 2 + fused combine: out += gate * (h @ W2 + b2) --------

__global__ __launch_bounds__(256, 4) void gemm_ffn2(
    const bf16* __restrict__ hbuf, const bf16* __restrict__ W2T,
    const bf16* __restrict__ sW2T, const float* __restrict__ b2,
    const float* __restrict__ sb2, const int* __restrict__ segstart,
    const int* __restrict__ tiles, const int* __restrict__ numtiles,
    const int* __restrict__ rowtok, const float* __restrict__ slotgate,
    float* __restrict__ out) {
  const int NC = 6, G = 4;
  int nt = *numtiles;
  int work = xcd_work(blockIdx.x + NC * blockIdx.y, nt * NC);
  if (work < 0) return;
  int tileG = work / (NC * G);
  int rem = work - tileG * (NC * G);
  int tbase = tileG * G;
  int gl = nt - tbase; if (gl > G) gl = G;
  int colb = rem / gl;
  int gx = tbase + rem % gl;

  int seg = tiles[gx * 2], lt = tiles[gx * 2 + 1];
  int s0 = segstart[seg] + lt * 128;
  int send = segstart[seg + 1];
  const bf16* Bw = (seg < NEXP) ? W2T + (size_t)seg * H_DIM * D_DIM : sW2T;
  const float* bb = (seg < NEXP) ? b2 + seg * D_DIM : sb2;

  __shared__ __align__(16) bf16 As[2][128 * 32];
  __shared__ __align__(16) bf16 Bs[2][128 * 32];
  int tid = threadIdx.x, wave = tid >> 6, lane = tid & 63;
  int wr = wave >> 1, wc = wave & 1;
  int colbase = colb * 128;
  int q = lane >> 4, fr = lane & 15;
  int g8 = (((lane & 3) ^ ((lane >> 3) & 3))) * 8;
  int ls8 = (q ^ ((fr >> 1) & 3)) * 8;

  const bf16* aptr[2];
  const bf16* bptr[2];
#pragma unroll
  for (int p = 0; p < 2; p++) {
    int r = wave * 32 + p * 16 + (lane >> 2);
    int s = s0 + r;
    if (s > send - 1) s = send - 1;
    aptr[p] = hbuf + (size_t)s * H_DIM + g8;
    bptr[p] = Bw + (size_t)(colbase + r) * H_DIM + g8;
  }

  auto stage = [&](int buf, int ks) {
    int kk = ks * 32;
#pragma unroll
    for (int p = 0; p < 2; p++) {
      async16(&As[buf][(wave * 32 + p * 16) * 32], aptr[p] + kk);
      async16(&Bs[buf][(wave * 32 + p * 16) * 32], bptr[p] + kk);
    }
  };

  f32x4 acc[4][4];
#pragma unroll
  for (int m = 0; m < 4; m++)
#pragma unroll
    for (int n = 0; n < 4; n++) acc[m][n] = 0.f;

  stage(0, 0);
  WAIT_VM0();
  S_BARRIER();

#define NT2 96
  for (int ks = 0; ks < NT2; ks++) {
    if (ks + 1 < NT2) stage((ks + 1) & 1, ks + 1);
    const bf16* Ac = As[ks & 1];
    const bf16* Bc = Bs[ks & 1];
    short8 af[4], bfr[4];
#pragma unroll
    for (int m = 0; m < 4; m++)
      af[m] = *(const short8*)&Ac[(wr * 64 + m * 16 + fr) * 32 + ls8];
#pragma unroll
    for (int n = 0; n < 4; n++)
      bfr[n] = *(const short8*)&Bc[(wc * 64 + n * 16 + fr) * 32 + ls8];
    __builtin_amdgcn_s_setprio(1);
#pragma unroll
    for (int m = 0; m < 4; m++)
#pragma unroll
      for (int n = 0; n < 4; n++)
        acc[m][n] = __builtin_amdgcn_mfma_f32_16x16x32_bf16(af[m], bfr[n], acc[m][n], 0, 0, 0);
    __builtin_amdgcn_s_setprio(0);
    WAIT_VM0();
    S_BARRIER();
  }

  // fused combine: out[token][c] += gate * (acc + b2[c])  (gate=0 for pad rows)
  int tk[16];
  float sg[16];
#pragma unroll
  for (int m = 0; m < 4; m++)
#pragma unroll
    for (int j = 0; j < 4; j++) {
      int s = s0 + wr * 64 + m * 16 + q * 4 + j;
      bool valid = s < send;
      int sc = valid ? s : send - 1;
      tk[m * 4 + j] = rowtok[sc];
      sg[m * 4 + j] = valid ? slotgate[sc] : 0.f;
    }
#pragma unroll
  for (int n = 0; n < 4; n++) {
    int c = colbase + wc * 64 + n * 16 + fr;
    float bv = bb[c];
#pragma unroll
    for (int m = 0; m < 4; m++)
#pragma unroll
      for (int j = 0; j < 4; j++) {
        float v = (acc[m][n][j] + bv) * sg[m * 4 + j];
        atomicAdd(&out[(size_t)tk[m * 4 + j] * D_DIM + c], v);
      }
  }
}

// ---------------- host launch ----------------

extern "C" void kernel_launch(void* const* d_in, const int* in_sizes, int n_in,
                              void* d_out, int out_size, void* d_ws, size_t ws_size,
                              hipStream_t stream) {
  const float* x = (const float*)d_in[0];
  const float* Wlinear = (const float*)d_in[1];
  const float* learnedE = (const float*)d_in[2];
  const float* bias = (const float*)d_in[3];
  const float* W1 = (const float*)d_in[4];
  const float* b1 = (const float*)d_in[5];
  const float* W2 = (const float*)d_in[6];
  const float* b2 = (const float*)d_in[7];
  const float* sW1 = (const float*)d_in[8];
  const float* sb1 = (const float*)d_in[9];
  const float* sW2 = (const float*)d_in[10];
  const float* sb2 = (const float*)d_in[11];
  float* out = (float*)d_out;

  char* ws = (char*)d_ws;
  size_t off = 0;
  auto alloc = [&](size_t bytes) {
    char* p = ws + off;
    off += (bytes + 255) & ~(size_t)255;
    return p;
  };
  float* eHat = (float*)alloc(8 * 768 * 4);
  bf16* pHi = (bf16*)alloc((size_t)T_TOK * D_DIM * 2);
  bf16* pLo = (bf16*)alloc((size_t)T_TOK * D_DIM * 2);
  bf16* wHi = (bf16*)alloc((size_t)D_DIM * D_DIM * 2);
  bf16* wLo = (bf16*)alloc((size_t)D_DIM * D_DIM * 2);
  bf16* W1T = (bf16*)alloc((size_t)NEXP * D_DIM * H_DIM * 2);
  bf16* W2T = (bf16*)alloc((size_t)NEXP * D_DIM * H_DIM * 2);
  bf16* sW1T = (bf16*)alloc((size_t)D_DIM * H_DIM * 2);
  bf16* sW2T = (bf16*)alloc((size_t)D_DIM * H_DIM * 2);
  float* y = (float*)alloc((size_t)T_TOK * D_DIM * 4);
  bf16* hbuf = (bf16*)alloc((size_t)3 * T_TOK * H_DIM * 2);
  int* gidx = (int*)alloc(T_TOK * 2 * 4);
  float* gval = (float*)alloc(T_TOK * 2 * 4);
  int* rowtok = (int*)alloc(3 * T_TOK * 4);
  float* slotgate = (float*)alloc(3 * T_TOK * 4);
  int* counts = (int*)alloc(8 * 4);
  int* segstart = (int*)alloc(10 * 4);
  int* cursors = (int*)alloc(8 * 4);
  int* numtiles = (int*)alloc(4);
  int* tiles = (int*)alloc(MAXTILES * 2 * 4);
  (void)ws_size; (void)in_sizes; (void)n_in; (void)out_size;

  hipMemsetAsync(counts, 0, 8 * 4, stream);
  hipMemsetAsync(out, 0, (size_t)T_TOK * D_DIM * 4, stream);
  norm_learnedE<<<1, 256, 0, stream>>>(learnedE, eHat);
  cast_hilo<<<2048, 256, 0, stream>>>(x, pHi, pLo, T_TOK * D_DIM);
  cast_hilo<<<1024, 256, 0, stream>>>(Wlinear, wHi, wLo, D_DIM * D_DIM);
  transpose_cast<<<dim3(D_DIM / 32, H_DIM / 32, NEXP), 256, 0, stream>>>(W1, W1T, D_DIM, H_DIM);
  transpose_cast<<<dim3(H_DIM / 32, D_DIM / 32, NEXP), 256, 0, stream>>>(W2, W2T, H_DIM, D_DIM);
  transpose_cast<<<dim3(D_DIM / 32, H_DIM / 32, 1), 256, 0, stream>>>(sW1, sW1T, D_DIM, H_DIM);
  transpose_cast<<<dim3(H_DIM / 32, D_DIM / 32, 1), 256, 0, stream>>>(sW2, sW2T, H_DIM, D_DIM);

  gemm_router<<<294, 256, 0, stream>>>(pHi, pLo, wHi, wLo, y);
  router_epi<<<T_TOK / 4, 256, 0, stream>>>(y, eHat, bias, gidx, gval, counts);
  scan_build<<<1, 64, 0, stream>>>(counts, segstart, cursors, tiles, numtiles);
  fill_assign<<<(T_TOK + 255) / 256, 256, 0, stream>>>(gidx, gval, cursors, rowtok, slotgate);

  gemm_ffn1<<<dim3(24, MAXTILES), 256, 0, stream>>>(
      pHi, W1T, sW1T, b1, sb1, segstart, tiles, numtiles, rowtok, hbuf);
  gemm_ffn2<<<dim3(6, MAXTILES), 256, 0, stream>>>(
      hbuf, W2T, sW2T, b2, sb2, segstart, tiles, numtiles, rowtok, slotgate, out);
}

// Round 19
// 690.993 us; speedup vs baseline: 1.1280x; 1.0084x over previous
//
#include <hip/hip_runtime.h>
#include <hip/hip_bf16.h>

typedef __hip_bfloat16 bf16;
typedef __attribute__((ext_vector_type(8))) short short8;
typedef __attribute__((ext_vector_type(4))) float f32x4;

#define T_TOK 6272
#define D_DIM 768
#define H_DIM 3072
#define NEXP 8
#define MAXTILES 160
#define BKR 64

#define S_BARRIER() __builtin_amdgcn_s_barrier()
#define WAIT_VM0() asm volatile("s_waitcnt vmcnt(0)" ::: "memory")

__device__ __forceinline__ void async16(void* lds, const void* g) {
  __builtin_amdgcn_global_load_lds(
      (const __attribute__((address_space(1))) void*)g,
      (__attribute__((address_space(3))) void*)lds, 16, 0, 0);
}

// gelu(x) = 0.5*x*(1+erf(x/sqrt(2))), erf via Abramowitz-Stegun 7.1.26
__device__ __forceinline__ float gelu_f(float x) {
  float z = x * 0.70710678118654752f;
  float az = fabsf(z);
  float t = 1.f / (1.f + 0.3275911f * az);
  float poly = ((((1.061405429f * t - 1.453152027f) * t + 1.421413741f) * t -
                 0.284496736f) * t + 0.254829592f) * t;
  float e = __expf(-az * az);
  float er = 1.f - poly * e;
  er = copysignf(er, z);
  return 0.5f * x * (1.f + er);
}

// XCD-chunked bijective work decode (m204): physical id -> contiguous work
// range per XCD. nwr = total real works; returns -1 if dead block.
__device__ __forceinline__ int xcd_work(int orig, int nwr) {
  if (orig >= nwr) return -1;
  int xcd = orig & 7, pos = orig >> 3;
  int q = nwr >> 3, r = nwr & 7;
  return (xcd < r ? xcd * (q + 1) : r * (q + 1) + (xcd - r) * q) + pos;
}

// ---------------- small prep kernels ----------------

__global__ void cast_hilo(const float* __restrict__ in, bf16* __restrict__ hi,
                          bf16* __restrict__ lo, int n) {
  int i = blockIdx.x * blockDim.x + threadIdx.x;
  int stride = gridDim.x * blockDim.x;
  for (; i < n; i += stride) {
    float x = in[i];
    bf16 h = __float2bfloat16(x);
    hi[i] = h;
    lo[i] = __float2bfloat16(x - __bfloat162float(h));
  }
}

// in: [B][R][C] fp32 -> out: [B][C][R] bf16   (R,C multiples of 32)
__global__ void transpose_cast(const float* __restrict__ in, bf16* __restrict__ out,
                               int R, int C) {
  __shared__ float tile[32][33];
  int b = blockIdx.z;
  const float* ib = in + (size_t)b * R * C;
  bf16* ob = out + (size_t)b * R * C;
  int r0 = blockIdx.x * 32, c0 = blockIdx.y * 32;
  int tx = threadIdx.x & 31, ty = threadIdx.x >> 5;  // 32 x 8
  for (int i = 0; i < 32; i += 8)
    tile[ty + i][tx] = ib[(size_t)(r0 + ty + i) * C + c0 + tx];
  __syncthreads();
  for (int i = 0; i < 32; i += 8)
    ob[(size_t)(c0 + ty + i) * R + r0 + tx] = __float2bfloat16(tile[tx][ty + i]);
}

__global__ void norm_learnedE(const float* __restrict__ lE, float* __restrict__ eHat) {
  int wave = threadIdx.x >> 6, lane = threadIdx.x & 63;
  for (int e = wave; e < NEXP; e += 4) {
    float v[12];
    float ss = 0.f;
    for (int j = 0; j < 12; j++) {
      v[j] = lE[e * D_DIM + lane + 64 * j];
      ss += v[j] * v[j];
    }
    for (int o = 32; o; o >>= 1) ss += __shfl_xor(ss, o);
    float rn = 1.f / fmaxf(sqrtf(ss), 1e-12f);
    for (int j = 0; j < 12; j++) eHat[e * D_DIM + lane + 64 * j] = v[j] * rn;
  }
}

// ---- router GEMM (split-bf16, K'=3*768, BK=64, swizzled, dbuf, XCD-chunk) ---

__global__ __launch_bounds__(256, 2) void gemm_router(
    const bf16* __restrict__ pHi, const bf16* __restrict__ pLo,
    const bf16* __restrict__ wHi, const bf16* __restrict__ wLo,
    float* __restrict__ y) {
  // 49 row-tiles x 6 col-blocks = 294 works; col-fast, G=8 tile groups.
  int work = xcd_work(blockIdx.x, 294);
  int tileG = work / 48;
  int rem = work - tileG * 48;
  int base = tileG * 8;
  int gl = 49 - base; if (gl > 8) gl = 8;
  int colb = rem / gl;
  int rowt = base + rem % gl;

  __shared__ __align__(16) bf16 As[2][128 * BKR];
  __shared__ __align__(16) bf16 Bs[2][128 * BKR];
  int tid = threadIdx.x, wave = tid >> 6, lane = tid & 63;
  int wr = wave >> 1, wc = wave & 1;
  int rowbase = rowt * 128, colbase = colb * 128;
  int rslot = (lane & 7) ^ (lane >> 3);

  size_t aoff[4], boff[4];
#pragma unroll
  for (int c = 0; c < 4; c++) {
    int row = 32 * wave + 8 * c + (lane >> 3);
    aoff[c] = (size_t)(rowbase + row) * D_DIM + rslot * 8;
    boff[c] = (size_t)(colbase + row) * D_DIM + rslot * 8;
  }

  auto stage = [&](int buf, int ks) {
    int term = ks / 12;
    const bf16* A = (term == 1) ? pLo : pHi;
    const bf16* B = (term == 2) ? wLo : wHi;
    int kk = (ks - term * 12) * BKR;
#pragma unroll
    for (int c = 0; c < 4; c++) {
      async16(&As[buf][(32 * wave + 8 * c) * BKR], A + aoff[c] + kk);
      async16(&Bs[buf][(32 * wave + 8 * c) * BKR], B + boff[c] + kk);
    }
  };

  f32x4 acc[4][4];
#pragma unroll
  for (int m = 0; m < 4; m++)
#pragma unroll
    for (int n = 0; n < 4; n++) acc[m][n] = 0.f;

  stage(0, 0);
  __syncthreads();
  int cur = 0;
  int q = lane >> 4, fr = lane & 15;
  for (int ks = 0; ks < 36; ks++) {
    if (ks < 35) stage(cur ^ 1, ks + 1);
    const bf16* Ac = As[cur];
    const bf16* Bc = Bs[cur];
#pragma unroll
    for (int kh = 0; kh < 2; kh++) {
      short8 af[4], bfr[4];
#pragma unroll
      for (int m = 0; m < 4; m++) {
        int row = wr * 64 + m * 16 + fr;
        int ls = ((kh << 2) + q) ^ (row & 7);
        af[m] = *(const short8*)&Ac[row * BKR + ls * 8];
      }
#pragma unroll
      for (int n = 0; n < 4; n++) {
        int row = wc * 64 + n * 16 + fr;
        int ls = ((kh << 2) + q) ^ (row & 7);
        bfr[n] = *(const short8*)&Bc[row * BKR + ls * 8];
      }
#pragma unroll
      for (int m = 0; m < 4; m++)
#pragma unroll
        for (int n = 0; n < 4; n++)
          acc[m][n] = __builtin_amdgcn_mfma_f32_16x16x32_bf16(af[m], bfr[n], acc[m][n], 0, 0, 0);
    }
    __syncthreads();
    cur ^= 1;
  }
  for (int m = 0; m < 4; m++)
    for (int n = 0; n < 4; n++)
      for (int j = 0; j < 4; j++) {
        int r = rowbase + wr * 64 + m * 16 + (lane >> 4) * 4 + j;
        int c = colbase + wc * 64 + n * 16 + (lane & 15);
        y[(size_t)r * D_DIM + c] = acc[m][n][j];
      }
}

// ---------------- router epilogue ----------------

__global__ void router_epi(const float* __restrict__ y, const float* __restrict__ eHat,
                           const float* __restrict__ bias, int* __restrict__ gidx,
                           float* __restrict__ gval, int* __restrict__ counts) {
  int wave = threadIdx.x >> 6, lane = threadIdx.x & 63;
  int t = blockIdx.x * 4 + wave;
  float v[12];
  float ss = 0.f;
  for (int j = 0; j < 12; j++) {
    v[j] = y[(size_t)t * D_DIM + lane + 64 * j];
    ss += v[j] * v[j];
  }
  for (int o = 32; o; o >>= 1) ss += __shfl_xor(ss, o);
  float d[NEXP];
  for (int e = 0; e < NEXP; e++) {
    float s = 0.f;
    for (int j = 0; j < 12; j++) s += v[j] * eHat[e * D_DIM + lane + 64 * j];
    for (int o = 32; o; o >>= 1) s += __shfl_xor(s, o);
    d[e] = s;
  }
  if (lane == 0) {
    float rn = 1.f / fmaxf(sqrtf(ss), 1e-12f);
    float sc[NEXP], mx = -1e30f;
    for (int e = 0; e < NEXP; e++) {
      sc[e] = d[e] * rn + bias[t * NEXP + e];
      mx = fmaxf(mx, sc[e]);
    }
    float p[NEXP], sum = 0.f;
    for (int e = 0; e < NEXP; e++) {
      p[e] = expf(sc[e] - mx);
      sum += p[e];
    }
    float inv = 1.f / sum;
    int i1 = 0;
    for (int e = 1; e < NEXP; e++)
      if (sc[e] > sc[i1]) i1 = e;
    int i2 = -1;
    for (int e = 0; e < NEXP; e++) {
      if (e == i1) continue;
      if (i2 < 0 || sc[e] > sc[i2]) i2 = e;
    }
    gidx[t * 2] = i1;
    gidx[t * 2 + 1] = i2;
    gval[t * 2] = p[i1] * inv;
    gval[t * 2 + 1] = p[i2] * inv;
    atomicAdd(&counts[i1], 1);
    atomicAdd(&counts[i2], 1);
  }
}

// ---------------- segment bookkeeping (128-row tiles) ----------------

__global__ void scan_build(const int* __restrict__ counts, int* __restrict__ segstart,
                           int* __restrict__ cursors, int* __restrict__ tiles,
                           int* __restrict__ numtiles) {
  if (threadIdx.x == 0) {
    int off = 0;
    for (int e = 0; e < NEXP; e++) {
      segstart[e] = off;
      cursors[e] = off;
      off += counts[e];
    }
    segstart[NEXP] = off;              // == 2T
    segstart[NEXP + 1] = off + T_TOK;  // end of shared segment
    int nt = 0;
    for (int e = 0; e < NEXP + 1; e++) {
      int cnt = (e < NEXP) ? counts[e] : T_TOK;
      int ntl = (cnt + 127) >> 7;
      for (int l = 0; l < ntl; l++) {
        tiles[nt * 2] = e;
        tiles[nt * 2 + 1] = l;
        nt++;
      }
    }
    *numtiles = nt;
  }
}

__global__ void fill_assign(const int* __restrict__ gidx, int* __restrict__ cursors,
                            int* __restrict__ rowtok, int* __restrict__ slot_of) {
  int t = blockIdx.x * 256 + threadIdx.x;
  if (t >= T_TOK) return;
  for (int k = 0; k < 2; k++) {
    int e = gidx[t * 2 + k];
    int pos = atomicAdd(&cursors[e], 1);
    rowtok[pos] = t;
    slot_of[t * 2 + k] = pos;
  }
  rowtok[2 * T_TOK + t] = t;  // shared segment: identity
}

// ====== single-barrier 2-phase 128x128 / BK=32 grouped GEMM (R15 winner) =====
// Per K-step: issue STAGE(next buf) FIRST, then ds_read(cur)+MFMA, then ONE
// vmcnt(0)+barrier. XCD-chunked col-fast work order with G-tile super-groups.
// Streaming intermediates (hbuf, moebuf) stored non-temporal to keep the
// L2-resident W1/W2 panels hot.

// ---- grouped FFN GEMM 1: h = gelu(Xg @ W1 + b1), K = 768 (24 K-steps) -------

__global__ __launch_bounds__(256, 4) void gemm_ffn1(
    const bf16* __restrict__ pHi, const bf16* __restrict__ W1T,
    const bf16* __restrict__ sW1T, const float* __restrict__ b1,
    const float* __restrict__ sb1, const int* __restrict__ segstart,
    const int* __restrict__ tiles, const int* __restrict__ numtiles,
    const int* __restrict__ rowtok, bf16* __restrict__ hbuf) {
  const int NC = 24, G = 16;
  int nt = *numtiles;
  int work = xcd_work(blockIdx.x + NC * blockIdx.y, nt * NC);
  if (work < 0) return;
  int tileG = work / (NC * G);
  int rem = work - tileG * (NC * G);
  int tbase = tileG * G;
  int gl = nt - tbase; if (gl > G) gl = G;
  int colb = rem / gl;
  int gx = tbase + rem % gl;

  int seg = tiles[gx * 2], lt = tiles[gx * 2 + 1];
  int s0 = segstart[seg] + lt * 128;
  int send = segstart[seg + 1];
  const bf16* Bw = (seg < NEXP) ? W1T + (size_t)seg * H_DIM * D_DIM : sW1T;
  const float* bb = (seg < NEXP) ? b1 + seg * H_DIM : sb1;

  __shared__ __align__(16) bf16 As[2][128 * 32];
  __shared__ __align__(16) bf16 Bs[2][128 * 32];
  int tid = threadIdx.x, wave = tid >> 6, lane = tid & 63;
  int wr = wave >> 1, wc = wave & 1;
  int colbase = colb * 128;
  int q = lane >> 4, fr = lane & 15;
  int g8 = (((lane & 3) ^ ((lane >> 3) & 3))) * 8;  // inverse-swizzled src slot
  int ls8 = (q ^ ((fr >> 1) & 3)) * 8;              // swizzled read slot

  const bf16* aptr[2];
  const bf16* bptr[2];
#pragma unroll
  for (int p = 0; p < 2; p++) {
    int r = wave * 32 + p * 16 + (lane >> 2);
    int s = s0 + r;
    if (s > send - 1) s = send - 1;
    aptr[p] = pHi + (size_t)rowtok[s] * D_DIM + g8;
    bptr[p] = Bw + (size_t)(colbase + r) * D_DIM + g8;
  }

  auto stage = [&](int buf, int ks) {
    int kk = ks * 32;
#pragma unroll
    for (int p = 0; p < 2; p++) {
      async16(&As[buf][(wave * 32 + p * 16) * 32], aptr[p] + kk);
      async16(&Bs[buf][(wave * 32 + p * 16) * 32], bptr[p] + kk);
    }
  };

  f32x4 acc[4][4];
#pragma unroll
  for (int m = 0; m < 4; m++)
#pragma unroll
    for (int n = 0; n < 4; n++) acc[m][n] = 0.f;

  stage(0, 0);
  WAIT_VM0();
  S_BARRIER();

#define NT1 24
  for (int ks = 0; ks < NT1; ks++) {
    if (ks + 1 < NT1) stage((ks + 1) & 1, ks + 1);  // issue next-tile loads FIRST
    const bf16* Ac = As[ks & 1];
    const bf16* Bc = Bs[ks & 1];
    short8 af[4], bfr[4];
#pragma unroll
    for (int m = 0; m < 4; m++)
      af[m] = *(const short8*)&Ac[(wr * 64 + m * 16 + fr) * 32 + ls8];
#pragma unroll
    for (int n = 0; n < 4; n++)
      bfr[n] = *(const short8*)&Bc[(wc * 64 + n * 16 + fr) * 32 + ls8];
    __builtin_amdgcn_s_setprio(1);
#pragma unroll
    for (int m = 0; m < 4; m++)
#pragma unroll
      for (int n = 0; n < 4; n++)
        acc[m][n] = __builtin_amdgcn_mfma_f32_16x16x32_bf16(af[m], bfr[n], acc[m][n], 0, 0, 0);
    __builtin_amdgcn_s_setprio(0);
    WAIT_VM0();  // next-tile stores landed (had the whole read+MFMA window)
    S_BARRIER();
  }
#pragma unroll
  for (int n = 0; n < 4; n++) {
    int c = colbase + wc * 64 + n * 16 + fr;
    float bv = bb[c];
#pragma unroll
    for (int m = 0; m < 4; m++)
#pragma unroll
      for (int j = 0; j < 4; j++) {
        int s = s0 + wr * 64 + m * 16 + q * 4 + j;
        if (s < send) {
          float xv = acc[m][n][j] + bv;
          bf16 hv = __float2bfloat16(gelu_f(xv));
          __builtin_nontemporal_store(
              *reinterpret_cast<short*>(&hv),
              reinterpret_cast<short*>(&hbuf[(size_t)s * H_DIM + c]));
        }
      }
  }
}

// ---- grouped FFN GEMM 2: eo = h @ W2 + b2, K = 3072 (96 K-steps) ------------

__global__ __launch_bounds__(256, 4) void gemm_ffn2(
    const bf16* __restrict__ hbuf, const bf16* __restrict__ W2T,
    const bf16* __restrict__ sW2T, const float* __restrict__ b2,
    const float* __restrict__ sb2, const int* __restrict__ segstart,
    const int* __restrict__ tiles, const int* __restrict__ numtiles,
    float* __restrict__ moebuf) {
  const int NC = 6, G = 4;
  int nt = *numtiles;
  int work = xcd_work(blockIdx.x + NC * blockIdx.y, nt * NC);
  if (work < 0) return;
  int tileG = work / (NC * G);
  int rem = work - tileG * (NC * G);
  int tbase = tileG * G;
  int gl = nt - tbase; if (gl > G) gl = G;
  int colb = rem / gl;
  int gx = tbase + rem % gl;

  int seg = tiles[gx * 2], lt = tiles[gx * 2 + 1];
  int s0 = segstart[seg] + lt * 128;
  int send = segstart[seg + 1];
  const bf16* Bw = (seg < NEXP) ? W2T + (size_t)seg * H_DIM * D_DIM : sW2T;
  const float* bb = (seg < NEXP) ? b2 + seg * D_DIM : sb2;

  __shared__ __align__(16) bf16 As[2][128 * 32];
  __shared__ __align__(16) bf16 Bs[2][128 * 32];
  int tid = threadIdx.x, wave = tid >> 6, lane = tid & 63;
  int wr = wave >> 1, wc = wave & 1;
  int colbase = colb * 128;
  int q = lane >> 4, fr = lane & 15;
  int g8 = (((lane & 3) ^ ((lane >> 3) & 3))) * 8;
  int ls8 = (q ^ ((fr >> 1) & 3)) * 8;

  const bf16* aptr[2];
  const bf16* bptr[2];
#pragma unroll
  for (int p = 0; p < 2; p++) {
    int r = wave * 32 + p * 16 + (lane >> 2);
    int s = s0 + r;
    if (s > send - 1) s = send - 1;
    aptr[p] = hbuf + (size_t)s * H_DIM + g8;
    bptr[p] = Bw + (size_t)(colbase + r) * H_DIM + g8;
  }

  auto stage = [&](int buf, int ks) {
    int kk = ks * 32;
#pragma unroll
    for (int p = 0; p < 2; p++) {
      async16(&As[buf][(wave * 32 + p * 16) * 32], aptr[p] + kk);
      async16(&Bs[buf][(wave * 32 + p * 16) * 32], bptr[p] + kk);
    }
  };

  f32x4 acc[4][4];
#pragma unroll
  for (int m = 0; m < 4; m++)
#pragma unroll
    for (int n = 0; n < 4; n++) acc[m][n] = 0.f;

  stage(0, 0);
  WAIT_VM0();
  S_BARRIER();

#define NT2 96
  for (int ks = 0; ks < NT2; ks++) {
    if (ks + 1 < NT2) stage((ks + 1) & 1, ks + 1);
    const bf16* Ac = As[ks & 1];
    const bf16* Bc = Bs[ks & 1];
    short8 af[4], bfr[4];
#pragma unroll
    for (int m = 0; m < 4; m++)
      af[m] = *(const short8*)&Ac[(wr * 64 + m * 16 + fr) * 32 + ls8];
#pragma unroll
    for (int n = 0; n < 4; n++)
      bfr[n] = *(const short8*)&Bc[(wc * 64 + n * 16 + fr) * 32 + ls8];
    __builtin_amdgcn_s_setprio(1);
#pragma unroll
    for (int m = 0; m < 4; m++)
#pragma unroll
      for (int n = 0; n < 4; n++)
        acc[m][n] = __builtin_amdgcn_mfma_f32_16x16x32_bf16(af[m], bfr[n], acc[m][n], 0, 0, 0);
    __builtin_amdgcn_s_setprio(0);
    WAIT_VM0();
    S_BARRIER();
  }
#pragma unroll
  for (int n = 0; n < 4; n++) {
    int c = colbase + wc * 64 + n * 16 + fr;
    float bv = bb[c];
#pragma unroll
    for (int m = 0; m < 4; m++)
#pragma unroll
      for (int j = 0; j < 4; j++) {
        int s = s0 + wr * 64 + m * 16 + q * 4 + j;
        if (s < send)
          __builtin_nontemporal_store(acc[m][n][j] + bv,
                                      &moebuf[(size_t)s * D_DIM + c]);
      }
  }
}

// ---------------- final combine ----------------

__global__ void combine_out(const float* __restrict__ moebuf, const float* __restrict__ gval,
                            const int* __restrict__ slot_of, float* __restrict__ out) {
  int i = blockIdx.x * 256 + threadIdx.x;
  const int total = T_TOK * (D_DIM / 4);
  if (i >= total) return;
  int t = i / (D_DIM / 4), c = i % (D_DIM / 4);
  float g0 = gval[2 * t], g1 = gval[2 * t + 1];
  int sA = slot_of[2 * t], sB = slot_of[2 * t + 1];
  const f32x4* pa = (const f32x4*)(moebuf + (size_t)sA * D_DIM) + c;
  const f32x4* pb = (const f32x4*)(moebuf + (size_t)sB * D_DIM) + c;
  const f32x4* ps = (const f32x4*)(moebuf + (size_t)(2 * T_TOK + t) * D_DIM) + c;
  f32x4 r = g0 * (*pa) + g1 * (*pb) + *ps;
  ((f32x4*)out)[i] = r;
}

// ---------------- host launch ----------------

extern "C" void kernel_launch(void* const* d_in, const int* in_sizes, int n_in,
                              void* d_out, int out_size, void* d_ws, size_t ws_size,
                              hipStream_t stream) {
  const float* x = (const float*)d_in[0];
  const float* Wlinear = (const float*)d_in[1];
  const float* learnedE = (const float*)d_in[2];
  const float* bias = (const float*)d_in[3];
  const float* W1 = (const float*)d_in[4];
  const float* b1 = (const float*)d_in[5];
  const float* W2 = (const float*)d_in[6];
  const float* b2 = (const float*)d_in[7];
  const float* sW1 = (const float*)d_in[8];
  const float* sb1 = (const float*)d_in[9];
  const float* sW2 = (const float*)d_in[10];
  const float* sb2 = (const float*)d_in[11];
  float* out = (float*)d_out;

  char* ws = (char*)d_ws;
  size_t off = 0;
  auto alloc = [&](size_t bytes) {
    char* p = ws + off;
    off += (bytes + 255) & ~(size_t)255;
    return p;
  };
  float* eHat = (float*)alloc(8 * 768 * 4);
  bf16* pHi = (bf16*)alloc((size_t)T_TOK * D_DIM * 2);
  bf16* pLo = (bf16*)alloc((size_t)T_TOK * D_DIM * 2);
  bf16* wHi = (bf16*)alloc((size_t)D_DIM * D_DIM * 2);
  bf16* wLo = (bf16*)alloc((size_t)D_DIM * D_DIM * 2);
  bf16* W1T = (bf16*)alloc((size_t)NEXP * D_DIM * H_DIM * 2);
  bf16* W2T = (bf16*)alloc((size_t)NEXP * D_DIM * H_DIM * 2);
  bf16* sW1T = (bf16*)alloc((size_t)D_DIM * H_DIM * 2);
  bf16* sW2T = (bf16*)alloc((size_t)D_DIM * H_DIM * 2);
  float* y = (float*)alloc((size_t)T_TOK * D_DIM * 4);
  bf16* hbuf = (bf16*)alloc((size_t)3 * T_TOK * H_DIM * 2);
  float* moebuf = (float*)alloc((size_t)3 * T_TOK * D_DIM * 4);
  int* gidx = (int*)alloc(T_TOK * 2 * 4);
  float* gval = (float*)alloc(T_TOK * 2 * 4);
  int* rowtok = (int*)alloc(3 * T_TOK * 4);
  int* slot_of = (int*)alloc(T_TOK * 2 * 4);
  int* counts = (int*)alloc(8 * 4);
  int* segstart = (int*)alloc(10 * 4);
  int* cursors = (int*)alloc(8 * 4);
  int* numtiles = (int*)alloc(4);
  int* tiles = (int*)alloc(MAXTILES * 2 * 4);
  (void)ws_size; (void)in_sizes; (void)n_in; (void)out_size;

  hipMemsetAsync(counts, 0, 8 * 4, stream);
  norm_learnedE<<<1, 256, 0, stream>>>(learnedE, eHat);
  cast_hilo<<<2048, 256, 0, stream>>>(x, pHi, pLo, T_TOK * D_DIM);
  cast_hilo<<<1024, 256, 0, stream>>>(Wlinear, wHi, wLo, D_DIM * D_DIM);
  transpose_cast<<<dim3(D_DIM / 32, H_DIM / 32, NEXP), 256, 0, stream>>>(W1, W1T, D_DIM, H_DIM);
  transpose_cast<<<dim3(H_DIM / 32, D_DIM / 32, NEXP), 256, 0, stream>>>(W2, W2T, H_DIM, D_DIM);
  transpose_cast<<<dim3(D_DIM / 32, H_DIM / 32, 1), 256, 0, stream>>>(sW1, sW1T, D_DIM, H_DIM);
  transpose_cast<<<dim3(H_DIM / 32, D_DIM / 32, 1), 256, 0, stream>>>(sW2, sW2T, H_DIM, D_DIM);

  gemm_router<<<294, 256, 0, stream>>>(pHi, pLo, wHi, wLo, y);
  router_epi<<<T_TOK / 4, 256, 0, stream>>>(y, eHat, bias, gidx, gval, counts);
  scan_build<<<1, 64, 0, stream>>>(counts, segstart, cursors, tiles, numtiles);
  fill_assign<<<(T_TOK + 255) / 256, 256, 0, stream>>>(gidx, cursors, rowtok, slot_of);

  gemm_ffn1<<<dim3(24, MAXTILES), 256, 0, stream>>>(
      pHi, W1T, sW1T, b1, sb1, segstart, tiles, numtiles, rowtok, hbuf);
  gemm_ffn2<<<dim3(6, MAXTILES), 256, 0, stream>>>(
      hbuf, W2T, sW2T, b2, sb2, segstart, tiles, numtiles, moebuf);

  combine_out<<<(T_TOK * (D_DIM / 4) + 255) / 256, 256, 0, stream>>>(moebuf, gval, slot_of, out);
}

// Round 20
// 670.419 us; speedup vs baseline: 1.1626x; 1.0307x over previous
//
#include <hip/hip_runtime.h>
#include <hip/hip_bf16.h>

typedef __hip_bfloat16 bf16;
typedef __attribute__((ext_vector_type(8))) short short8;
typedef __attribute__((ext_vector_type(4))) float f32x4;

#define T_TOK 6272
#define D_DIM 768
#define H_DIM 3072
#define NEXP 8
#define MAXTILES 160
#define BKR 64

#define S_BARRIER() __builtin_amdgcn_s_barrier()
#define WAIT_VM0() asm volatile("s_waitcnt vmcnt(0)" ::: "memory")

__device__ __forceinline__ void async16(void* lds, const void* g) {
  __builtin_amdgcn_global_load_lds(
      (const __attribute__((address_space(1))) void*)g,
      (__attribute__((address_space(3))) void*)lds, 16, 0, 0);
}

// gelu(x) = 0.5*x*(1+erf(x/sqrt(2))), erf via Abramowitz-Stegun 7.1.26
__device__ __forceinline__ float gelu_f(float x) {
  float z = x * 0.70710678118654752f;
  float az = fabsf(z);
  float t = 1.f / (1.f + 0.3275911f * az);
  float poly = ((((1.061405429f * t - 1.453152027f) * t + 1.421413741f) * t -
                 0.284496736f) * t + 0.254829592f) * t;
  float e = __expf(-az * az);
  float er = 1.f - poly * e;
  er = copysignf(er, z);
  return 0.5f * x * (1.f + er);
}

// XCD-chunked bijective work decode (m204): physical id -> contiguous work
// range per XCD. nwr = total real works; returns -1 if dead block.
__device__ __forceinline__ int xcd_work(int orig, int nwr) {
  if (orig >= nwr) return -1;
  int xcd = orig & 7, pos = orig >> 3;
  int q = nwr >> 3, r = nwr & 7;
  return (xcd < r ? xcd * (q + 1) : r * (q + 1) + (xcd - r) * q) + pos;
}

// ---------------- small prep kernels ----------------

__global__ void cast_hilo(const float* __restrict__ in, bf16* __restrict__ hi,
                          bf16* __restrict__ lo, int n) {
  int i = blockIdx.x * blockDim.x + threadIdx.x;
  int stride = gridDim.x * blockDim.x;
  for (; i < n; i += stride) {
    float x = in[i];
    bf16 h = __float2bfloat16(x);
    hi[i] = h;
    lo[i] = __float2bfloat16(x - __bfloat162float(h));
  }
}

// in: [B][R][C] fp32 -> out: [B][C][R] bf16   (R,C multiples of 32)
__global__ void transpose_cast(const float* __restrict__ in, bf16* __restrict__ out,
                               int R, int C) {
  __shared__ float tile[32][33];
  int b = blockIdx.z;
  const float* ib = in + (size_t)b * R * C;
  bf16* ob = out + (size_t)b * R * C;
  int r0 = blockIdx.x * 32, c0 = blockIdx.y * 32;
  int tx = threadIdx.x & 31, ty = threadIdx.x >> 5;  // 32 x 8
  for (int i = 0; i < 32; i += 8)
    tile[ty + i][tx] = ib[(size_t)(r0 + ty + i) * C + c0 + tx];
  __syncthreads();
  for (int i = 0; i < 32; i += 8)
    ob[(size_t)(c0 + ty + i) * R + r0 + tx] = __float2bfloat16(tile[tx][ty + i]);
}

__global__ void norm_learnedE(const float* __restrict__ lE, float* __restrict__ eHat) {
  int wave = threadIdx.x >> 6, lane = threadIdx.x & 63;
  for (int e = wave; e < NEXP; e += 4) {
    float v[12];
    float ss = 0.f;
    for (int j = 0; j < 12; j++) {
      v[j] = lE[e * D_DIM + lane + 64 * j];
      ss += v[j] * v[j];
    }
    for (int o = 32; o; o >>= 1) ss += __shfl_xor(ss, o);
    float rn = 1.f / fmaxf(sqrtf(ss), 1e-12f);
    for (int j = 0; j < 12; j++) eHat[e * D_DIM + lane + 64 * j] = v[j] * rn;
  }
}

// ---- router GEMM (split-bf16, K'=3*768, BK=64, swizzled, dbuf, XCD-chunk) ---

__global__ __launch_bounds__(256, 2) void gemm_router(
    const bf16* __restrict__ pHi, const bf16* __restrict__ pLo,
    const bf16* __restrict__ wHi, const bf16* __restrict__ wLo,
    float* __restrict__ y) {
  // 49 row-tiles x 6 col-blocks = 294 works; col-fast, G=8 tile groups.
  int work = xcd_work(blockIdx.x, 294);
  int tileG = work / 48;
  int rem = work - tileG * 48;
  int base = tileG * 8;
  int gl = 49 - base; if (gl > 8) gl = 8;
  int colb = rem / gl;
  int rowt = base + rem % gl;

  __shared__ __align__(16) bf16 As[2][128 * BKR];
  __shared__ __align__(16) bf16 Bs[2][128 * BKR];
  int tid = threadIdx.x, wave = tid >> 6, lane = tid & 63;
  int wr = wave >> 1, wc = wave & 1;
  int rowbase = rowt * 128, colbase = colb * 128;
  int rslot = (lane & 7) ^ (lane >> 3);

  size_t aoff[4], boff[4];
#pragma unroll
  for (int c = 0; c < 4; c++) {
    int row = 32 * wave + 8 * c + (lane >> 3);
    aoff[c] = (size_t)(rowbase + row) * D_DIM + rslot * 8;
    boff[c] = (size_t)(colbase + row) * D_DIM + rslot * 8;
  }

  auto stage = [&](int buf, int ks) {
    int term = ks / 12;
    const bf16* A = (term == 1) ? pLo : pHi;
    const bf16* B = (term == 2) ? wLo : wHi;
    int kk = (ks - term * 12) * BKR;
#pragma unroll
    for (int c = 0; c < 4; c++) {
      async16(&As[buf][(32 * wave + 8 * c) * BKR], A + aoff[c] + kk);
      async16(&Bs[buf][(32 * wave + 8 * c) * BKR], B + boff[c] + kk);
    }
  };

  f32x4 acc[4][4];
#pragma unroll
  for (int m = 0; m < 4; m++)
#pragma unroll
    for (int n = 0; n < 4; n++) acc[m][n] = 0.f;

  stage(0, 0);
  __syncthreads();
  int cur = 0;
  int q = lane >> 4, fr = lane & 15;
  for (int ks = 0; ks < 36; ks++) {
    if (ks < 35) stage(cur ^ 1, ks + 1);
    const bf16* Ac = As[cur];
    const bf16* Bc = Bs[cur];
#pragma unroll
    for (int kh = 0; kh < 2; kh++) {
      short8 af[4], bfr[4];
#pragma unroll
      for (int m = 0; m < 4; m++) {
        int row = wr * 64 + m * 16 + fr;
        int ls = ((kh << 2) + q) ^ (row & 7);
        af[m] = *(const short8*)&Ac[row * BKR + ls * 8];
      }
#pragma unroll
      for (int n = 0; n < 4; n++) {
        int row = wc * 64 + n * 16 + fr;
        int ls = ((kh << 2) + q) ^ (row & 7);
        bfr[n] = *(const short8*)&Bc[row * BKR + ls * 8];
      }
#pragma unroll
      for (int m = 0; m < 4; m++)
#pragma unroll
        for (int n = 0; n < 4; n++)
          acc[m][n] = __builtin_amdgcn_mfma_f32_16x16x32_bf16(af[m], bfr[n], acc[m][n], 0, 0, 0);
    }
    __syncthreads();
    cur ^= 1;
  }
  for (int m = 0; m < 4; m++)
    for (int n = 0; n < 4; n++)
      for (int j = 0; j < 4; j++) {
        int r = rowbase + wr * 64 + m * 16 + (lane >> 4) * 4 + j;
        int c = colbase + wc * 64 + n * 16 + (lane & 15);
        y[(size_t)r * D_DIM + c] = acc[m][n][j];
      }
}

// ---------------- router epilogue ----------------

__global__ void router_epi(const float* __restrict__ y, const float* __restrict__ eHat,
                           const float* __restrict__ bias, int* __restrict__ gidx,
                           float* __restrict__ gval, int* __restrict__ counts) {
  int wave = threadIdx.x >> 6, lane = threadIdx.x & 63;
  int t = blockIdx.x * 4 + wave;
  float v[12];
  float ss = 0.f;
  for (int j = 0; j < 12; j++) {
    v[j] = y[(size_t)t * D_DIM + lane + 64 * j];
    ss += v[j] * v[j];
  }
  for (int o = 32; o; o >>= 1) ss += __shfl_xor(ss, o);
  float d[NEXP];
  for (int e = 0; e < NEXP; e++) {
    float s = 0.f;
    for (int j = 0; j < 12; j++) s += v[j] * eHat[e * D_DIM + lane + 64 * j];
    for (int o = 32; o; o >>= 1) s += __shfl_xor(s, o);
    d[e] = s;
  }
  if (lane == 0) {
    float rn = 1.f / fmaxf(sqrtf(ss), 1e-12f);
    float sc[NEXP], mx = -1e30f;
    for (int e = 0; e < NEXP; e++) {
      sc[e] = d[e] * rn + bias[t * NEXP + e];
      mx = fmaxf(mx, sc[e]);
    }
    float p[NEXP], sum = 0.f;
    for (int e = 0; e < NEXP; e++) {
      p[e] = expf(sc[e] - mx);
      sum += p[e];
    }
    float inv = 1.f / sum;
    int i1 = 0;
    for (int e = 1; e < NEXP; e++)
      if (sc[e] > sc[i1]) i1 = e;
    int i2 = -1;
    for (int e = 0; e < NEXP; e++) {
      if (e == i1) continue;
      if (i2 < 0 || sc[e] > sc[i2]) i2 = e;
    }
    gidx[t * 2] = i1;
    gidx[t * 2 + 1] = i2;
    gval[t * 2] = p[i1] * inv;
    gval[t * 2 + 1] = p[i2] * inv;
    atomicAdd(&counts[i1], 1);
    atomicAdd(&counts[i2], 1);
  }
}

// ---------------- segment bookkeeping (128-row tiles) ----------------

__global__ void scan_build(const int* __restrict__ counts, int* __restrict__ segstart,
                           int* __restrict__ cursors, int* __restrict__ tiles,
                           int* __restrict__ numtiles) {
  if (threadIdx.x == 0) {
    int off = 0;
    for (int e = 0; e < NEXP; e++) {
      segstart[e] = off;
      cursors[e] = off;
      off += counts[e];
    }
    segstart[NEXP] = off;              // == 2T
    segstart[NEXP + 1] = off + T_TOK;  // end of shared segment
    int nt = 0;
    for (int e = 0; e < NEXP + 1; e++) {
      int cnt = (e < NEXP) ? counts[e] : T_TOK;
      int ntl = (cnt + 127) >> 7;
      for (int l = 0; l < ntl; l++) {
        tiles[nt * 2] = e;
        tiles[nt * 2 + 1] = l;
        nt++;
      }
    }
    *numtiles = nt;
  }
}

__global__ void fill_assign(const int* __restrict__ gidx, int* __restrict__ cursors,
                            int* __restrict__ rowtok, int* __restrict__ slot_of) {
  int t = blockIdx.x * 256 + threadIdx.x;
  if (t >= T_TOK) return;
  for (int k = 0; k < 2; k++) {
    int e = gidx[t * 2 + k];
    int pos = atomicAdd(&cursors[e], 1);
    rowtok[pos] = t;
    slot_of[t * 2 + k] = pos;
  }
  rowtok[2 * T_TOK + t] = t;  // shared segment: identity
}

// ====== single-barrier 2-phase 128x128 / BK=32 grouped GEMM (R15 winner) =====
// Per K-step: issue STAGE(next buf) FIRST, then ds_read(cur)+MFMA, then ONE
// vmcnt(0)+barrier. XCD-chunked col-fast work order with G-tile super-groups.

// ---- grouped FFN GEMM 1: h = gelu(Xg @ W1 + b1), K = 768 (24 K-steps) -------

__global__ __launch_bounds__(256, 4) void gemm_ffn1(
    const bf16* __restrict__ pHi, const bf16* __restrict__ W1T,
    const bf16* __restrict__ sW1T, const float* __restrict__ b1,
    const float* __restrict__ sb1, const int* __restrict__ segstart,
    const int* __restrict__ tiles, const int* __restrict__ numtiles,
    const int* __restrict__ rowtok, bf16* __restrict__ hbuf) {
  const int NC = 24, G = 16;
  int nt = *numtiles;
  int work = xcd_work(blockIdx.x + NC * blockIdx.y, nt * NC);
  if (work < 0) return;
  int tileG = work / (NC * G);
  int rem = work - tileG * (NC * G);
  int tbase = tileG * G;
  int gl = nt - tbase; if (gl > G) gl = G;
  int colb = rem / gl;
  int gx = tbase + rem % gl;

  int seg = tiles[gx * 2], lt = tiles[gx * 2 + 1];
  int s0 = segstart[seg] + lt * 128;
  int send = segstart[seg + 1];
  const bf16* Bw = (seg < NEXP) ? W1T + (size_t)seg * H_DIM * D_DIM : sW1T;
  const float* bb = (seg < NEXP) ? b1 + seg * H_DIM : sb1;

  __shared__ __align__(16) bf16 As[2][128 * 32];
  __shared__ __align__(16) bf16 Bs[2][128 * 32];
  int tid = threadIdx.x, wave = tid >> 6, lane = tid & 63;
  int wr = wave >> 1, wc = wave & 1;
  int colbase = colb * 128;
  int q = lane >> 4, fr = lane & 15;
  int g8 = (((lane & 3) ^ ((lane >> 3) & 3))) * 8;  // inverse-swizzled src slot
  int ls8 = (q ^ ((fr >> 1) & 3)) * 8;              // swizzled read slot

  const bf16* aptr[2];
  const bf16* bptr[2];
#pragma unroll
  for (int p = 0; p < 2; p++) {
    int r = wave * 32 + p * 16 + (lane >> 2);
    int s = s0 + r;
    if (s > send - 1) s = send - 1;
    aptr[p] = pHi + (size_t)rowtok[s] * D_DIM + g8;
    bptr[p] = Bw + (size_t)(colbase + r) * D_DIM + g8;
  }

  auto stage = [&](int buf, int ks) {
    int kk = ks * 32;
#pragma unroll
    for (int p = 0; p < 2; p++) {
      async16(&As[buf][(wave * 32 + p * 16) * 32], aptr[p] + kk);
      async16(&Bs[buf][(wave * 32 + p * 16) * 32], bptr[p] + kk);
    }
  };

  f32x4 acc[4][4];
#pragma unroll
  for (int m = 0; m < 4; m++)
#pragma unroll
    for (int n = 0; n < 4; n++) acc[m][n] = 0.f;

  stage(0, 0);
  WAIT_VM0();
  S_BARRIER();

#define NT1 24
  for (int ks = 0; ks < NT1; ks++) {
    if (ks + 1 < NT1) stage((ks + 1) & 1, ks + 1);  // issue next-tile loads FIRST
    const bf16* Ac = As[ks & 1];
    const bf16* Bc = Bs[ks & 1];
    short8 af[4], bfr[4];
#pragma unroll
    for (int m = 0; m < 4; m++)
      af[m] = *(const short8*)&Ac[(wr * 64 + m * 16 + fr) * 32 + ls8];
#pragma unroll
    for (int n = 0; n < 4; n++)
      bfr[n] = *(const short8*)&Bc[(wc * 64 + n * 16 + fr) * 32 + ls8];
    __builtin_amdgcn_s_setprio(1);
#pragma unroll
    for (int m = 0; m < 4; m++)
#pragma unroll
      for (int n = 0; n < 4; n++)
        acc[m][n] = __builtin_amdgcn_mfma_f32_16x16x32_bf16(af[m], bfr[n], acc[m][n], 0, 0, 0);
    __builtin_amdgcn_s_setprio(0);
    WAIT_VM0();  // next-tile stores landed (had the whole read+MFMA window)
    S_BARRIER();
  }
#pragma unroll
  for (int n = 0; n < 4; n++) {
    int c = colbase + wc * 64 + n * 16 + fr;
    float bv = bb[c];
#pragma unroll
    for (int m = 0; m < 4; m++)
#pragma unroll
      for (int j = 0; j < 4; j++) {
        int s = s0 + wr * 64 + m * 16 + q * 4 + j;
        if (s < send) {
          float xv = acc[m][n][j] + bv;
          hbuf[(size_t)s * H_DIM + c] = __float2bfloat16(gelu_f(xv));
        }
      }
  }
}

// ---- grouped FFN GEMM 2: eo = h @ W2 + b2, K = 3072 (96 K-steps) ------------

__global__ __launch_bounds__(256, 4) void gemm_ffn2(
    const bf16* __restrict__ hbuf, const bf16* __restrict__ W2T,
    const bf16* __restrict__ sW2T, const float* __restrict__ b2,
    const float* __restrict__ sb2, const int* __restrict__ segstart,
    const int* __restrict__ tiles, const int* __restrict__ numtiles,
    float* __restrict__ moebuf) {
  const int NC = 6, G = 4;
  int nt = *numtiles;
  int work = xcd_work(blockIdx.x + NC * blockIdx.y, nt * NC);
  if (work < 0) return;
  int tileG = work / (NC * G);
  int rem = work - tileG * (NC * G);
  int tbase = tileG * G;
  int gl = nt - tbase; if (gl > G) gl = G;
  int colb = rem / gl;
  int gx = tbase + rem % gl;

  int seg = tiles[gx * 2], lt = tiles[gx * 2 + 1];
  int s0 = segstart[seg] + lt * 128;
  int send = segstart[seg + 1];
  const bf16* Bw = (seg < NEXP) ? W2T + (size_t)seg * H_DIM * D_DIM : sW2T;
  const float* bb = (seg < NEXP) ? b2 + seg * D_DIM : sb2;

  __shared__ __align__(16) bf16 As[2][128 * 32];
  __shared__ __align__(16) bf16 Bs[2][128 * 32];
  int tid = threadIdx.x, wave = tid >> 6, lane = tid & 63;
  int wr = wave >> 1, wc = wave & 1;
  int colbase = colb * 128;
  int q = lane >> 4, fr = lane & 15;
  int g8 = (((lane & 3) ^ ((lane >> 3) & 3))) * 8;
  int ls8 = (q ^ ((fr >> 1) & 3)) * 8;

  const bf16* aptr[2];
  const bf16* bptr[2];
#pragma unroll
  for (int p = 0; p < 2; p++) {
    int r = wave * 32 + p * 16 + (lane >> 2);
    int s = s0 + r;
    if (s > send - 1) s = send - 1;
    aptr[p] = hbuf + (size_t)s * H_DIM + g8;
    bptr[p] = Bw + (size_t)(colbase + r) * H_DIM + g8;
  }

  auto stage = [&](int buf, int ks) {
    int kk = ks * 32;
#pragma unroll
    for (int p = 0; p < 2; p++) {
      async16(&As[buf][(wave * 32 + p * 16) * 32], aptr[p] + kk);
      async16(&Bs[buf][(wave * 32 + p * 16) * 32], bptr[p] + kk);
    }
  };

  f32x4 acc[4][4];
#pragma unroll
  for (int m = 0; m < 4; m++)
#pragma unroll
    for (int n = 0; n < 4; n++) acc[m][n] = 0.f;

  stage(0, 0);
  WAIT_VM0();
  S_BARRIER();

#define NT2 96
  for (int ks = 0; ks < NT2; ks++) {
    if (ks + 1 < NT2) stage((ks + 1) & 1, ks + 1);
    const bf16* Ac = As[ks & 1];
    const bf16* Bc = Bs[ks & 1];
    short8 af[4], bfr[4];
#pragma unroll
    for (int m = 0; m < 4; m++)
      af[m] = *(const short8*)&Ac[(wr * 64 + m * 16 + fr) * 32 + ls8];
#pragma unroll
    for (int n = 0; n < 4; n++)
      bfr[n] = *(const short8*)&Bc[(wc * 64 + n * 16 + fr) * 32 + ls8];
    __builtin_amdgcn_s_setprio(1);
#pragma unroll
    for (int m = 0; m < 4; m++)
#pragma unroll
      for (int n = 0; n < 4; n++)
        acc[m][n] = __builtin_amdgcn_mfma_f32_16x16x32_bf16(af[m], bfr[n], acc[m][n], 0, 0, 0);
    __builtin_amdgcn_s_setprio(0);
    WAIT_VM0();
    S_BARRIER();
  }
#pragma unroll
  for (int n = 0; n < 4; n++) {
    int c = colbase + wc * 64 + n * 16 + fr;
    float bv = bb[c];
#pragma unroll
    for (int m = 0; m < 4; m++)
#pragma unroll
      for (int j = 0; j < 4; j++) {
        int s = s0 + wr * 64 + m * 16 + q * 4 + j;
        if (s < send) moebuf[(size_t)s * D_DIM + c] = acc[m][n][j] + bv;
      }
  }
}

// ---------------- final combine ----------------

__global__ void combine_out(const float* __restrict__ moebuf, const float* __restrict__ gval,
                            const int* __restrict__ slot_of, float* __restrict__ out) {
  int i = blockIdx.x * 256 + threadIdx.x;
  const int total = T_TOK * (D_DIM / 4);
  if (i >= total) return;
  int t = i / (D_DIM / 4), c = i % (D_DIM / 4);
  float g0 = gval[2 * t], g1 = gval[2 * t + 1];
  int sA = slot_of[2 * t], sB = slot_of[2 * t + 1];
  const f32x4* pa = (const f32x4*)(moebuf + (size_t)sA * D_DIM) + c;
  const f32x4* pb = (const f32x4*)(moebuf + (size_t)sB * D_DIM) + c;
  const f32x4* ps = (const f32x4*)(moebuf + (size_t)(2 * T_TOK + t) * D_DIM) + c;
  f32x4 r = g0 * (*pa) + g1 * (*pb) + *ps;
  ((f32x4*)out)[i] = r;
}

// ---------------- host launch ----------------

extern "C" void kernel_launch(void* const* d_in, const int* in_sizes, int n_in,
                              void* d_out, int out_size, void* d_ws, size_t ws_size,
                              hipStream_t stream) {
  const float* x = (const float*)d_in[0];
  const float* Wlinear = (const float*)d_in[1];
  const float* learnedE = (const float*)d_in[2];
  const float* bias = (const float*)d_in[3];
  const float* W1 = (const float*)d_in[4];
  const float* b1 = (const float*)d_in[5];
  const float* W2 = (const float*)d_in[6];
  const float* b2 = (const float*)d_in[7];
  const float* sW1 = (const float*)d_in[8];
  const float* sb1 = (const float*)d_in[9];
  const float* sW2 = (const float*)d_in[10];
  const float* sb2 = (const float*)d_in[11];
  float* out = (float*)d_out;

  char* ws = (char*)d_ws;
  size_t off = 0;
  auto alloc = [&](size_t bytes) {
    char* p = ws + off;
    off += (bytes + 255) & ~(size_t)255;
    return p;
  };
  float* eHat = (float*)alloc(8 * 768 * 4);
  bf16* pHi = (bf16*)alloc((size_t)T_TOK * D_DIM * 2);
  bf16* pLo = (bf16*)alloc((size_t)T_TOK * D_DIM * 2);
  bf16* wHi = (bf16*)alloc((size_t)D_DIM * D_DIM * 2);
  bf16* wLo = (bf16*)alloc((size_t)D_DIM * D_DIM * 2);
  bf16* W1T = (bf16*)alloc((size_t)NEXP * D_DIM * H_DIM * 2);
  bf16* W2T = (bf16*)alloc((size_t)NEXP * D_DIM * H_DIM * 2);
  bf16* sW1T = (bf16*)alloc((size_t)D_DIM * H_DIM * 2);
  bf16* sW2T = (bf16*)alloc((size_t)D_DIM * H_DIM * 2);
  float* y = (float*)alloc((size_t)T_TOK * D_DIM * 4);
  bf16* hbuf = (bf16*)alloc((size_t)3 * T_TOK * H_DIM * 2);
  float* moebuf = (float*)alloc((size_t)3 * T_TOK * D_DIM * 4);
  int* gidx = (int*)alloc(T_TOK * 2 * 4);
  float* gval = (float*)alloc(T_TOK * 2 * 4);
  int* rowtok = (int*)alloc(3 * T_TOK * 4);
  int* slot_of = (int*)alloc(T_TOK * 2 * 4);
  int* counts = (int*)alloc(8 * 4);
  int* segstart = (int*)alloc(10 * 4);
  int* cursors = (int*)alloc(8 * 4);
  int* numtiles = (int*)alloc(4);
  int* tiles = (int*)alloc(MAXTILES * 2 * 4);
  (void)ws_size; (void)in_sizes; (void)n_in; (void)out_size;

  hipMemsetAsync(counts, 0, 8 * 4, stream);
  norm_learnedE<<<1, 256, 0, stream>>>(learnedE, eHat);
  cast_hilo<<<2048, 256, 0, stream>>>(x, pHi, pLo, T_TOK * D_DIM);
  cast_hilo<<<1024, 256, 0, stream>>>(Wlinear, wHi, wLo, D_DIM * D_DIM);
  transpose_cast<<<dim3(D_DIM / 32, H_DIM / 32, NEXP), 256, 0, stream>>>(W1, W1T, D_DIM, H_DIM);
  transpose_cast<<<dim3(H_DIM / 32, D_DIM / 32, NEXP), 256, 0, stream>>>(W2, W2T, H_DIM, D_DIM);
  transpose_cast<<<dim3(D_DIM / 32, H_DIM / 32, 1), 256, 0, stream>>>(sW1, sW1T, D_DIM, H_DIM);
  transpose_cast<<<dim3(H_DIM / 32, D_DIM / 32, 1), 256, 0, stream>>>(sW2, sW2T, H_DIM, D_DIM);

  gemm_router<<<294, 256, 0, stream>>>(pHi, pLo, wHi, wLo, y);
  router_epi<<<T_TOK / 4, 256, 0, stream>>>(y, eHat, bias, gidx, gval, counts);
  scan_build<<<1, 64, 0, stream>>>(counts, segstart, cursors, tiles, numtiles);
  fill_assign<<<(T_TOK + 255) / 256, 256, 0, stream>>>(gidx, cursors, rowtok, slot_of);

  gemm_ffn1<<<dim3(24, MAXTILES), 256, 0, stream>>>(
      pHi, W1T, sW1T, b1, sb1, segstart, tiles, numtiles, rowtok, hbuf);
  gemm_ffn2<<<dim3(6, MAXTILES), 256, 0, stream>>>(
      hbuf, W2T, sW2T, b2, sb2, segstart, tiles, numtiles, moebuf);

  combine_out<<<(T_TOK * (D_DIM / 4) + 255) / 256, 256, 0, stream>>>(moebuf, gval, slot_of, out);
}